// Round 3
// baseline (2179.030 us; speedup 1.0000x reference)
//
#include <hip/hip_runtime.h>
#include <hip/hip_bf16.h>
#include <stdint.h>

#define T_TOK   8192
#define D_HID   768
#define NE      8
#define FFN_DIM 3072
#define NCLS    191
#define NBATCH  256
#define NSEQ    32
#define NSLOT   (T_TOK * 2)
#define LN_EPS  1e-5f
#define OUT_N   (NBATCH * NCLS)   // 48896 logits + 1 aux

typedef __bf16 bf16x8 __attribute__((ext_vector_type(8)));
typedef float  f32x4  __attribute__((ext_vector_type(4)));

static __device__ __forceinline__ float bf2f(unsigned short u) {
    return __uint_as_float(((unsigned)u) << 16);
}
static __device__ __forceinline__ unsigned short f2bf(float f) {
    unsigned x = __float_as_uint(f);
    unsigned r = (x + 0x7fffu + ((x >> 16) & 1u)) >> 16;   // RNE
    return (unsigned short)r;
}

// ---------------- init ----------------
__global__ void k_zero(float* __restrict__ out, unsigned* __restrict__ counts,
                       unsigned* __restrict__ cursors, float* __restrict__ zsum,
                       float* __restrict__ loadsum) {
    int i = blockIdx.x * 256 + threadIdx.x;
    if (i < OUT_N + 1) out[i] = 0.0f;
    if (i < NE) { counts[i] = 0u; cursors[i] = 0u; loadsum[i] = 0.0f; }
    if (i == 0) zsum[0] = 0.0f;
}

// ---------------- fp32 GEMM (router GEMM1 only; must stay fp32 for exact top-2) ----------------
__global__ __launch_bounds__(256) void k_gemm_f32(
    const float* __restrict__ A, const float* __restrict__ B,
    const float* __restrict__ bias, float* __restrict__ C,
    int M, int N, int K) {
    const int m0 = blockIdx.y * 64, n0 = blockIdx.x * 64;
    __shared__ float As[16][68];
    __shared__ float Bs[16][68];
    const int tid = threadIdx.x;
    const int lr = tid >> 2, lc = (tid & 3) * 4;
    const int bkr = tid >> 4, bc = (tid & 15) * 4;
    const int tx = tid & 15, ty = tid >> 4;
    float acc[4][4] = {};
    const float* Arow = A + (size_t)(m0 + lr) * K;
    for (int k0 = 0; k0 < K; k0 += 16) {
        float4 av = *reinterpret_cast<const float4*>(Arow + k0 + lc);
        As[lc + 0][lr] = av.x; As[lc + 1][lr] = av.y;
        As[lc + 2][lr] = av.z; As[lc + 3][lr] = av.w;
        float4 bv = *reinterpret_cast<const float4*>(B + (size_t)(k0 + bkr) * N + n0 + bc);
        *reinterpret_cast<float4*>(&Bs[bkr][bc]) = bv;
        __syncthreads();
        #pragma unroll
        for (int k = 0; k < 16; ++k) {
            float a[4], bb[4];
            #pragma unroll
            for (int i = 0; i < 4; ++i) a[i] = As[k][ty * 4 + i];
            #pragma unroll
            for (int j = 0; j < 4; ++j) bb[j] = Bs[k][tx * 4 + j];
            #pragma unroll
            for (int i = 0; i < 4; ++i)
                #pragma unroll
                for (int j = 0; j < 4; ++j) acc[i][j] = fmaf(a[i], bb[j], acc[i][j]);
        }
        __syncthreads();
    }
    #pragma unroll
    for (int i = 0; i < 4; ++i) {
        const int r = m0 + ty * 4 + i, cb = n0 + tx * 4;
        float4 o;
        o.x = acc[i][0] + bias[cb + 0];
        o.y = acc[i][1] + bias[cb + 1];
        o.z = acc[i][2] + bias[cb + 2];
        o.w = acc[i][3] + bias[cb + 3];
        *reinterpret_cast<float4*>(C + (size_t)r * N + cb) = o;
    }
}

// ---------------- row LayerNorm + ReLU (fp32 buffer) ----------------
__global__ __launch_bounds__(256) void k_ln_relu_f32(
    float* __restrict__ Xb, int W, const float* __restrict__ g,
    const float* __restrict__ b, const unsigned* __restrict__ eos) {
    const int row = blockIdx.x;
    if (eos) { unsigned e = eos[row]; g += (size_t)e * W; b += (size_t)e * W; }
    float* x = Xb + (size_t)row * W;
    float s = 0.f, s2 = 0.f;
    for (int k = threadIdx.x; k < W; k += 256) { float v = x[k]; s += v; s2 += v * v; }
    __shared__ float rs[4], rs2[4], mv[2];
    #pragma unroll
    for (int o = 32; o > 0; o >>= 1) { s += __shfl_down(s, o); s2 += __shfl_down(s2, o); }
    const int wv = threadIdx.x >> 6, ln = threadIdx.x & 63;
    if (ln == 0) { rs[wv] = s; rs2[wv] = s2; }
    __syncthreads();
    if (threadIdx.x == 0) {
        float ts = rs[0] + rs[1] + rs[2] + rs[3];
        float ts2 = rs2[0] + rs2[1] + rs2[2] + rs2[3];
        float m = ts / W;
        float var = ts2 / W - m * m;
        mv[0] = m; mv[1] = rsqrtf(var + LN_EPS);
    }
    __syncthreads();
    float m = mv[0], r = mv[1];
    for (int k = threadIdx.x; k < W; k += 256) {
        float v = (x[k] - m) * r * g[k] + b[k];
        x[k] = fmaxf(v, 0.f);
    }
}

// ---------------- row LayerNorm + ReLU (bf16 buffer) ----------------
__global__ __launch_bounds__(256) void k_ln_relu_bf16(
    unsigned short* __restrict__ Xb, int W, const float* __restrict__ g,
    const float* __restrict__ b, const unsigned* __restrict__ eos) {
    const int row = blockIdx.x;
    unsigned e = eos[row];
    g += (size_t)e * W; b += (size_t)e * W;
    unsigned short* x = Xb + (size_t)row * W;
    float s = 0.f, s2 = 0.f;
    for (int k = threadIdx.x; k < W; k += 256) { float v = bf2f(x[k]); s += v; s2 += v * v; }
    __shared__ float rs[4], rs2[4], mv[2];
    #pragma unroll
    for (int o = 32; o > 0; o >>= 1) { s += __shfl_down(s, o); s2 += __shfl_down(s2, o); }
    const int wv = threadIdx.x >> 6, ln = threadIdx.x & 63;
    if (ln == 0) { rs[wv] = s; rs2[wv] = s2; }
    __syncthreads();
    if (threadIdx.x == 0) {
        float ts = rs[0] + rs[1] + rs[2] + rs[3];
        float ts2 = rs2[0] + rs2[1] + rs2[2] + rs2[3];
        float m = ts / W;
        float var = ts2 / W - m * m;
        mv[0] = m; mv[1] = rsqrtf(var + LN_EPS);
    }
    __syncthreads();
    float m = mv[0], r = mv[1];
    for (int k = threadIdx.x; k < W; k += 256) {
        float v = (bf2f(x[k]) - m) * r * g[k] + b[k];
        x[k] = f2bf(fmaxf(v, 0.f));
    }
}

// ---------------- router: logits, softmax, top-2, losses, counts (fp32) ----------------
__global__ __launch_bounds__(256) void k_router(
    const float* __restrict__ HR, const float* __restrict__ RW2, const float* __restrict__ RB2,
    unsigned* __restrict__ toke, float* __restrict__ tokw,
    unsigned* __restrict__ counts, float* __restrict__ zsum, float* __restrict__ loadsum) {
    const int wv = threadIdx.x >> 6, ln = threadIdx.x & 63;
    const int t = blockIdx.x * 4 + wv;
    __shared__ float part[4][64][9];
    float p[NE] = {};
    const float* hrow = HR + (size_t)t * D_HID;
    for (int k = ln; k < D_HID; k += 64) {
        float h = hrow[k];
        const float* w = RW2 + (size_t)k * NE;
        #pragma unroll
        for (int j = 0; j < NE; ++j) p[j] += h * w[j];
    }
    #pragma unroll
    for (int j = 0; j < NE; ++j) part[wv][ln][j] = p[j];
    __syncthreads();
    if (ln < NE) {
        float sj = 0.f;
        for (int l = 0; l < 64; ++l) sj += part[wv][l][ln];
        part[wv][0][ln] = sj + RB2[ln];
    }
    __syncthreads();
    if (ln == 0) {
        float lg[NE];
        #pragma unroll
        for (int j = 0; j < NE; ++j) lg[j] = part[wv][0][j];
        float mx = lg[0];
        #pragma unroll
        for (int j = 1; j < NE; ++j) mx = fmaxf(mx, lg[j]);
        float ex[NE], se = 0.f;
        #pragma unroll
        for (int j = 0; j < NE; ++j) { ex[j] = expf(lg[j] - mx); se += ex[j]; }
        float lse = logf(se) + mx;
        atomicAdd(zsum, lse * lse);
        int i0 = 0;
        #pragma unroll
        for (int j = 1; j < NE; ++j) if (ex[j] > ex[i0]) i0 = j;
        int i1 = (i0 == 0) ? 1 : 0;
        #pragma unroll
        for (int j = 0; j < NE; ++j) if (j != i0 && ex[j] > ex[i1]) i1 = j;
        float w0 = ex[i0] / (ex[i0] + ex[i1]);
        float w1 = 1.0f - w0;
        toke[t * 2 + 0] = (unsigned)i0; toke[t * 2 + 1] = (unsigned)i1;
        tokw[t * 2 + 0] = w0;           tokw[t * 2 + 1] = w1;
        atomicAdd(&counts[i0], 1u); atomicAdd(&counts[i1], 1u);
        atomicAdd(&loadsum[i0], w0); atomicAdd(&loadsum[i1], w1);
    }
}

__global__ void k_prefix(const unsigned* __restrict__ counts, unsigned* __restrict__ offs) {
    if (threadIdx.x == 0) {
        unsigned o = 0;
        for (int e = 0; e < NE; ++e) { offs[e] = o; o += counts[e]; }
    }
}

__global__ void k_scatter(const unsigned* __restrict__ toke, const float* __restrict__ tokw,
                          const unsigned* __restrict__ offs, unsigned* __restrict__ cursors,
                          unsigned* __restrict__ tokv, unsigned* __restrict__ eosv,
                          float* __restrict__ wslot) {
    int t = blockIdx.x * 256 + threadIdx.x;
    if (t >= T_TOK) return;
    #pragma unroll
    for (int k = 0; k < 2; ++k) {
        unsigned e = toke[t * 2 + k];
        unsigned slot = offs[e] + atomicAdd(&cursors[e], 1u);
        tokv[slot] = (unsigned)t;
        eosv[slot] = e;
        wslot[slot] = tokw[t * 2 + k];
    }
}

// ============ MFMA grouped GEMM1: gathered x(f32->bf16) @ split-bf16 ew1 -> h1(bf16) ============
// 128x128 tile, BK=32, 4 waves 2x2, per-wave 64x64 (4x4 frags of 16x16x32).
__global__ __launch_bounds__(256) void k_gemm1_mfma(
    const float* __restrict__ X, const float* __restrict__ EW1, const float* __restrict__ EB1,
    const unsigned* __restrict__ tokv, const unsigned* __restrict__ offs,
    const unsigned* __restrict__ counts, unsigned short* __restrict__ H1) {
    const int e = blockIdx.z;
    const unsigned cnt = counts[e];
    const int m0 = blockIdx.y * 128;
    if ((unsigned)m0 >= cnt) return;
    const unsigned base = offs[e];
    const int n0 = blockIdx.x * 128;
    const float* __restrict__ W = EW1 + (size_t)e * D_HID * FFN_DIM;
    __shared__ unsigned short As[128][40];   // [m][k] bf16, pad->80B rows (16B aligned)
    __shared__ unsigned short Bh[128][40];   // [n][k] hi
    __shared__ unsigned short Bl[128][40];   // [n][k] lo
    __shared__ unsigned stok[128];
    const int tid = threadIdx.x;
    if (tid < 128) {
        unsigned rr = (unsigned)(m0 + tid);
        stok[tid] = tokv[base + ((rr < cnt) ? rr : (cnt - 1u))];
    }
    __syncthreads();
    const int wv = tid >> 6, ln = tid & 63;
    const int m_off = (wv >> 1) * 64, n_off = (wv & 1) * 64;
    const int lrow = ln & 15, lkg = ln >> 4;
    const int ar = tid >> 1, ah = (tid & 1) * 16;   // A staging: row, 16-float half
    const int bk = tid >> 3, bs = (tid & 7) * 16;   // B staging: k-row, 16-col seg
    f32x4 acc[4][4] = {};
    const float* aptr = X + (size_t)stok[ar] * D_HID + ah;
    for (int k0 = 0; k0 < D_HID; k0 += 32) {
        {   // stage A: fp32 -> bf16
            const float* src = aptr + k0;
            unsigned short tmp[16];
            #pragma unroll
            for (int q = 0; q < 4; ++q) {
                float4 v = *reinterpret_cast<const float4*>(src + q * 4);
                tmp[q*4+0]=f2bf(v.x); tmp[q*4+1]=f2bf(v.y);
                tmp[q*4+2]=f2bf(v.z); tmp[q*4+3]=f2bf(v.w);
            }
            *reinterpret_cast<uint4*>(&As[ar][ah])     = *reinterpret_cast<uint4*>(&tmp[0]);
            *reinterpret_cast<uint4*>(&As[ar][ah + 8]) = *reinterpret_cast<uint4*>(&tmp[8]);
        }
        {   // stage B: fp32 -> (hi,lo) bf16, transposed [n][k]
            const float* src = W + (size_t)(k0 + bk) * FFN_DIM + n0 + bs;
            #pragma unroll
            for (int q = 0; q < 4; ++q) {
                float4 v = *reinterpret_cast<const float4*>(src + q * 4);
                float f[4] = {v.x, v.y, v.z, v.w};
                #pragma unroll
                for (int j = 0; j < 4; ++j) {
                    int n = bs + q * 4 + j;
                    unsigned short hi = f2bf(f[j]);
                    Bh[n][bk] = hi;
                    Bl[n][bk] = f2bf(f[j] - bf2f(hi));
                }
            }
        }
        __syncthreads();
        bf16x8 a[4];
        #pragma unroll
        for (int i = 0; i < 4; ++i)
            a[i] = *reinterpret_cast<const bf16x8*>(&As[m_off + i * 16 + lrow][lkg * 8]);
        #pragma unroll
        for (int j = 0; j < 4; ++j) {
            bf16x8 bh = *reinterpret_cast<const bf16x8*>(&Bh[n_off + j * 16 + lrow][lkg * 8]);
            bf16x8 bl = *reinterpret_cast<const bf16x8*>(&Bl[n_off + j * 16 + lrow][lkg * 8]);
            #pragma unroll
            for (int i = 0; i < 4; ++i) {
                acc[i][j] = __builtin_amdgcn_mfma_f32_16x16x32_bf16(a[i], bh, acc[i][j], 0, 0, 0);
                acc[i][j] = __builtin_amdgcn_mfma_f32_16x16x32_bf16(a[i], bl, acc[i][j], 0, 0, 0);
            }
        }
        __syncthreads();
    }
    const float* bias = EB1 + (size_t)e * FFN_DIM + n0;
    #pragma unroll
    for (int i = 0; i < 4; ++i) {
        #pragma unroll
        for (int r = 0; r < 4; ++r) {
            unsigned rr = (unsigned)(m0 + m_off + i * 16 + lkg * 4 + r);
            if (rr < cnt) {
                unsigned short* dst = H1 + (size_t)(base + rr) * FFN_DIM + n0;
                #pragma unroll
                for (int j = 0; j < 4; ++j) {
                    int c = n_off + j * 16 + lrow;
                    dst[c] = f2bf(acc[i][j][r] + bias[c]);
                }
            }
        }
    }
}

// ============ MFMA grouped GEMM2: h1(bf16) @ split-bf16 ew2 -> h2(f32) ============
__global__ __launch_bounds__(256) void k_gemm2_mfma(
    const unsigned short* __restrict__ H1, const float* __restrict__ EW2,
    const float* __restrict__ EB2, const unsigned* __restrict__ offs,
    const unsigned* __restrict__ counts, float* __restrict__ H2) {
    const int e = blockIdx.z;
    const unsigned cnt = counts[e];
    const int m0 = blockIdx.y * 128;
    if ((unsigned)m0 >= cnt) return;
    const unsigned base = offs[e];
    const int n0 = blockIdx.x * 128;
    const float* __restrict__ W = EW2 + (size_t)e * FFN_DIM * D_HID;
    __shared__ unsigned short As[128][40];
    __shared__ unsigned short Bh[128][40];
    __shared__ unsigned short Bl[128][40];
    const int tid = threadIdx.x;
    const int wv = tid >> 6, ln = tid & 63;
    const int m_off = (wv >> 1) * 64, n_off = (wv & 1) * 64;
    const int lrow = ln & 15, lkg = ln >> 4;
    const int ar = tid >> 1, ah = (tid & 1) * 16;
    const int bk = tid >> 3, bs = (tid & 7) * 16;
    unsigned arow = (unsigned)(m0 + ar);
    if (arow >= cnt) arow = cnt - 1u;
    const unsigned short* aptr = H1 + (size_t)(base + arow) * FFN_DIM + ah;
    f32x4 acc[4][4] = {};
    for (int k0 = 0; k0 < FFN_DIM; k0 += 32) {
        {   // stage A: bf16 direct
            const unsigned short* src = aptr + k0;
            *reinterpret_cast<uint4*>(&As[ar][ah])     = *reinterpret_cast<const uint4*>(src);
            *reinterpret_cast<uint4*>(&As[ar][ah + 8]) = *reinterpret_cast<const uint4*>(src + 8);
        }
        {   // stage B: fp32 -> (hi,lo) bf16, transposed [n][k]
            const float* src = W + (size_t)(k0 + bk) * D_HID + n0 + bs;
            #pragma unroll
            for (int q = 0; q < 4; ++q) {
                float4 v = *reinterpret_cast<const float4*>(src + q * 4);
                float f[4] = {v.x, v.y, v.z, v.w};
                #pragma unroll
                for (int j = 0; j < 4; ++j) {
                    int n = bs + q * 4 + j;
                    unsigned short hi = f2bf(f[j]);
                    Bh[n][bk] = hi;
                    Bl[n][bk] = f2bf(f[j] - bf2f(hi));
                }
            }
        }
        __syncthreads();
        bf16x8 a[4];
        #pragma unroll
        for (int i = 0; i < 4; ++i)
            a[i] = *reinterpret_cast<const bf16x8*>(&As[m_off + i * 16 + lrow][lkg * 8]);
        #pragma unroll
        for (int j = 0; j < 4; ++j) {
            bf16x8 bh = *reinterpret_cast<const bf16x8*>(&Bh[n_off + j * 16 + lrow][lkg * 8]);
            bf16x8 bl = *reinterpret_cast<const bf16x8*>(&Bl[n_off + j * 16 + lrow][lkg * 8]);
            #pragma unroll
            for (int i = 0; i < 4; ++i) {
                acc[i][j] = __builtin_amdgcn_mfma_f32_16x16x32_bf16(a[i], bh, acc[i][j], 0, 0, 0);
                acc[i][j] = __builtin_amdgcn_mfma_f32_16x16x32_bf16(a[i], bl, acc[i][j], 0, 0, 0);
            }
        }
        __syncthreads();
    }
    const float* bias = EB2 + (size_t)e * D_HID + n0;
    #pragma unroll
    for (int i = 0; i < 4; ++i) {
        #pragma unroll
        for (int r = 0; r < 4; ++r) {
            unsigned rr = (unsigned)(m0 + m_off + i * 16 + lkg * 4 + r);
            if (rr < cnt) {
                float* dst = H2 + (size_t)(base + rr) * D_HID + n0;
                #pragma unroll
                for (int j = 0; j < 4; ++j) {
                    int c = n_off + j * 16 + lrow;
                    dst[c] = acc[i][j][r] + bias[c];
                }
            }
        }
    }
}

// ---------------- GEMM3 + weighted scatter into output (fp32) ----------------
__global__ __launch_bounds__(256) void k_gemm3(
    const float* __restrict__ H2, const float* __restrict__ EW3, const float* __restrict__ EB3,
    const unsigned* __restrict__ tokv, const unsigned* __restrict__ eosv,
    const float* __restrict__ wslot, float* __restrict__ out) {
    const int slot = blockIdx.x;
    const unsigned e = eosv[slot], t = tokv[slot];
    const float wgt = wslot[slot] * (1.0f / NSEQ);
    __shared__ float sh[D_HID];
    const float* h = H2 + (size_t)slot * D_HID;
    for (int k = threadIdx.x; k < D_HID; k += 256) sh[k] = h[k];
    __syncthreads();
    const int c = threadIdx.x;
    if (c < NCLS) {
        const float* W3 = EW3 + (size_t)e * D_HID * NCLS + c;
        float acc = EB3[e * NCLS + c];
        #pragma unroll 8
        for (int k = 0; k < D_HID; ++k) acc = fmaf(sh[k], W3[(size_t)k * NCLS], acc);
        atomicAdd(&out[(t >> 5) * NCLS + c], wgt * acc);
    }
}

__global__ void k_aux(const float* __restrict__ zsum, const float* __restrict__ loadsum,
                      float* __restrict__ out) {
    if (threadIdx.x == 0) {
        float z = 0.1f * zsum[0] / (float)T_TOK;
        float lb = 0.f;
        for (int e = 0; e < NE; ++e) {
            float d = loadsum[e] / (float)T_TOK - 0.125f;
            lb += d * d;
        }
        out[OUT_N] = z + 0.1f * lb;
    }
}

extern "C" void kernel_launch(void* const* d_in, const int* in_sizes, int n_in,
                              void* d_out, int out_size, void* d_ws, size_t ws_size,
                              hipStream_t stream) {
    (void)in_sizes; (void)n_in; (void)out_size; (void)ws_size;
    const float* x    = (const float*)d_in[0];
    const float* rw1  = (const float*)d_in[1];
    const float* rb1  = (const float*)d_in[2];
    const float* rlg  = (const float*)d_in[3];
    const float* rlb  = (const float*)d_in[4];
    const float* rw2  = (const float*)d_in[5];
    const float* rb2  = (const float*)d_in[6];
    const float* ew1  = (const float*)d_in[7];
    const float* eb1  = (const float*)d_in[8];
    const float* el1g = (const float*)d_in[9];
    const float* el1b = (const float*)d_in[10];
    const float* ew2  = (const float*)d_in[11];
    const float* eb2  = (const float*)d_in[12];
    const float* el2g = (const float*)d_in[13];
    const float* el2b = (const float*)d_in[14];
    const float* ew3  = (const float*)d_in[15];
    const float* eb3  = (const float*)d_in[16];
    float* out = (float*)d_out;

    uint8_t* ws = (uint8_t*)d_ws;
    // [0, 50.3MB): hr (8192x768 f32) then h2 (16384x768 f32) — overlap, hr dead first
    float* hr = (float*)ws;
    float* h2 = (float*)ws;
    unsigned short* h1 = (unsigned short*)(ws + (size_t)50331648);   // 16384x3072 bf16
    uint8_t* sb = ws + (size_t)150994944;
    unsigned* tokv   = (unsigned*)sb;              // [NSLOT]
    unsigned* eosv   = tokv + NSLOT;               // [NSLOT]
    float*    wslot  = (float*)(eosv + NSLOT);     // [NSLOT]
    unsigned* toke   = (unsigned*)(wslot + NSLOT); // [T*2]
    float*    tokw   = (float*)(toke + NSLOT);     // [T*2]
    unsigned* counts = (unsigned*)(tokw + NSLOT);  // [8]
    unsigned* cursors = counts + NE;               // [8]
    unsigned* offs    = cursors + NE;              // [8]
    float*    zsum    = (float*)(offs + NE);       // [1]
    float*    loadsum = zsum + 1;                  // [8]

    k_zero<<<dim3(192), dim3(256), 0, stream>>>(out, counts, cursors, zsum, loadsum);
    k_gemm_f32<<<dim3(D_HID / 64, T_TOK / 64), dim3(256), 0, stream>>>(
        x, rw1, rb1, hr, T_TOK, D_HID, D_HID);
    k_ln_relu_f32<<<dim3(T_TOK), dim3(256), 0, stream>>>(hr, D_HID, rlg, rlb, nullptr);
    k_router<<<dim3(T_TOK / 4), dim3(256), 0, stream>>>(
        hr, rw2, rb2, toke, tokw, counts, zsum, loadsum);
    k_prefix<<<dim3(1), dim3(64), 0, stream>>>(counts, offs);
    k_scatter<<<dim3(T_TOK / 256), dim3(256), 0, stream>>>(
        toke, tokw, offs, cursors, tokv, eosv, wslot);
    k_gemm1_mfma<<<dim3(FFN_DIM / 128, T_TOK / 128, NE), dim3(256), 0, stream>>>(
        x, ew1, eb1, tokv, offs, counts, h1);
    k_ln_relu_bf16<<<dim3(NSLOT), dim3(256), 0, stream>>>(h1, FFN_DIM, el1g, el1b, eosv);
    k_gemm2_mfma<<<dim3(D_HID / 128, T_TOK / 128, NE), dim3(256), 0, stream>>>(
        h1, ew2, eb2, offs, counts, h2);
    k_ln_relu_f32<<<dim3(NSLOT), dim3(256), 0, stream>>>(h2, D_HID, el2g, el2b, eosv);
    k_gemm3<<<dim3(NSLOT), dim3(256), 0, stream>>>(h2, ew3, eb3, tokv, eosv, wslot, out);
    k_aux<<<dim3(1), dim3(64), 0, stream>>>(zsum, loadsum, out);
}

// Round 4
// 1735.904 us; speedup vs baseline: 1.2553x; 1.2553x over previous
//
#include <hip/hip_runtime.h>
#include <hip/hip_bf16.h>
#include <stdint.h>

#define T_TOK   8192
#define D_HID   768
#define NE      8
#define FFN_DIM 3072
#define NCLS    191
#define NSEQ    32
#define NSLOT   (T_TOK * 2)
#define NSLOTP  (NSLOT + 128)
#define LN_EPS  1e-5f
#define OUT_N   (256 * NCLS)   // 48896 logits + 1 aux

typedef __bf16 bf16x8 __attribute__((ext_vector_type(8)));
typedef float  f32x4  __attribute__((ext_vector_type(4)));

static __device__ __forceinline__ float bf2f(unsigned short u) {
    return __uint_as_float(((unsigned)u) << 16);
}
static __device__ __forceinline__ unsigned short f2bf_rn(float f) {
    return __builtin_bit_cast(unsigned short, (__bf16)f);
}
static __device__ __forceinline__ float bfround(float f) {
    return (float)((__bf16)f);
}

// ---------------- init ----------------
__global__ void k_zero(float* __restrict__ out, unsigned* __restrict__ counts,
                       unsigned* __restrict__ cursors, float* __restrict__ zsum,
                       float* __restrict__ loadsum) {
    int i = blockIdx.x * 256 + threadIdx.x;
    if (i < OUT_N + 1) out[i] = 0.0f;
    if (i < NE) { counts[i] = 0u; cursors[i] = 0u; loadsum[i] = 0.0f; }
    if (i == 0) zsum[0] = 0.0f;
}

// ======== router GEMM1 (x @ rw1 + rb1 -> hr f32), split-A x split-B MFMA ========
// M=8192 N=768 K=768, tile 128x128, BK=32, grid 384 (1D, XCD-swizzled, x-major)
__global__ __launch_bounds__(256) void k_rgemm_mfma(
    const float* __restrict__ X, const float* __restrict__ W,
    const float* __restrict__ bias, float* __restrict__ C) {
    const int bid = blockIdx.x;
    const int lid = (bid & 7) * 48 + (bid >> 3);       // 384 = 8 * 48, bijective
    const int m0 = (lid / 6) * 128, n0 = (lid % 6) * 128;
    __shared__ unsigned short Ah[128][40], Al[128][40];
    __shared__ unsigned short Bh[128][40], Bl[128][40];
    const int tid = threadIdx.x;
    const int wv = tid >> 6, ln = tid & 63;
    const int m_off = (wv >> 1) * 64, n_off = (wv & 1) * 64;
    const int lrow = ln & 15, lkg = ln >> 4;
    const int ar = tid >> 1, ahf = (tid & 1) * 16;
    const int bn = tid & 127, bq = tid >> 7;
    f32x4 acc[4][4] = {};
    const float* aptr = X + (size_t)(m0 + ar) * D_HID + ahf;
    for (int k0 = 0; k0 < D_HID; k0 += 32) {
        {   // A: fp32 -> hi/lo bf16, [m][k] rows, b128 writes
            unsigned short th[16], tl[16];
            #pragma unroll
            for (int q = 0; q < 4; ++q) {
                float4 v = *reinterpret_cast<const float4*>(aptr + k0 + q * 4);
                float fv[4] = {v.x, v.y, v.z, v.w};
                #pragma unroll
                for (int j = 0; j < 4; ++j) {
                    float hf = bfround(fv[j]);
                    th[q * 4 + j] = f2bf_rn(fv[j]);
                    tl[q * 4 + j] = f2bf_rn(fv[j] - hf);
                }
            }
            *reinterpret_cast<uint4*>(&Ah[ar][ahf])     = *reinterpret_cast<uint4*>(&th[0]);
            *reinterpret_cast<uint4*>(&Ah[ar][ahf + 8]) = *reinterpret_cast<uint4*>(&th[8]);
            *reinterpret_cast<uint4*>(&Al[ar][ahf])     = *reinterpret_cast<uint4*>(&tl[0]);
            *reinterpret_cast<uint4*>(&Al[ar][ahf + 8]) = *reinterpret_cast<uint4*>(&tl[8]);
        }
        {   // B: coalesced dword loads (fixed k row, consecutive n per lane),
            // per-thread: one n, 16 k -> two b128 writes per plane
            const float* wsrc = W + (size_t)(k0 + bq * 16) * D_HID + n0 + bn;
            unsigned short th[16], tl[16];
            #pragma unroll
            for (int kk = 0; kk < 16; ++kk) {
                float f = wsrc[(size_t)kk * D_HID];
                float hf = bfround(f);
                th[kk] = f2bf_rn(f);
                tl[kk] = f2bf_rn(f - hf);
            }
            *reinterpret_cast<uint4*>(&Bh[bn][bq * 16])     = *reinterpret_cast<uint4*>(&th[0]);
            *reinterpret_cast<uint4*>(&Bh[bn][bq * 16 + 8]) = *reinterpret_cast<uint4*>(&th[8]);
            *reinterpret_cast<uint4*>(&Bl[bn][bq * 16])     = *reinterpret_cast<uint4*>(&tl[0]);
            *reinterpret_cast<uint4*>(&Bl[bn][bq * 16 + 8]) = *reinterpret_cast<uint4*>(&tl[8]);
        }
        __syncthreads();
        bf16x8 a_h[4], a_l[4];
        #pragma unroll
        for (int i = 0; i < 4; ++i) {
            a_h[i] = *reinterpret_cast<const bf16x8*>(&Ah[m_off + i * 16 + lrow][lkg * 8]);
            a_l[i] = *reinterpret_cast<const bf16x8*>(&Al[m_off + i * 16 + lrow][lkg * 8]);
        }
        #pragma unroll
        for (int j = 0; j < 4; ++j) {
            bf16x8 b_h = *reinterpret_cast<const bf16x8*>(&Bh[n_off + j * 16 + lrow][lkg * 8]);
            bf16x8 b_l = *reinterpret_cast<const bf16x8*>(&Bl[n_off + j * 16 + lrow][lkg * 8]);
            #pragma unroll
            for (int i = 0; i < 4; ++i) {
                acc[i][j] = __builtin_amdgcn_mfma_f32_16x16x32_bf16(a_h[i], b_h, acc[i][j], 0, 0, 0);
                acc[i][j] = __builtin_amdgcn_mfma_f32_16x16x32_bf16(a_h[i], b_l, acc[i][j], 0, 0, 0);
                acc[i][j] = __builtin_amdgcn_mfma_f32_16x16x32_bf16(a_l[i], b_h, acc[i][j], 0, 0, 0);
            }
        }
        __syncthreads();
    }
    #pragma unroll
    for (int i = 0; i < 4; ++i)
        #pragma unroll
        for (int r = 0; r < 4; ++r) {
            int row = m0 + m_off + i * 16 + lkg * 4 + r;
            float* dst = C + (size_t)row * D_HID;
            #pragma unroll
            for (int j = 0; j < 4; ++j) {
                int c = n0 + n_off + j * 16 + lrow;
                dst[c] = acc[i][j][r] + bias[c];
            }
        }
}

// ---------------- LayerNorm+ReLU, W=768 fp32 ----------------
__global__ __launch_bounds__(256) void k_ln768_f32(
    float* __restrict__ Xb, const float* __restrict__ g, const float* __restrict__ b,
    const unsigned* __restrict__ eos, const unsigned* __restrict__ totp) {
    const int row = blockIdx.x;
    if (totp && (unsigned)row >= *totp) return;
    const float* gp = g; const float* bp = b;
    if (eos) { unsigned e = eos[row]; gp += (size_t)e * D_HID; bp += (size_t)e * D_HID; }
    float* x = Xb + (size_t)row * D_HID;
    const int tid = threadIdx.x;
    float v0 = x[tid], v1 = x[tid + 256], v2 = x[tid + 512];
    float s = v0 + v1 + v2, s2 = v0 * v0 + v1 * v1 + v2 * v2;
    __shared__ float rs[4], rs2[4], mv[2];
    #pragma unroll
    for (int o = 32; o > 0; o >>= 1) { s += __shfl_down(s, o); s2 += __shfl_down(s2, o); }
    const int wv = tid >> 6, ln = tid & 63;
    if (ln == 0) { rs[wv] = s; rs2[wv] = s2; }
    __syncthreads();
    if (tid == 0) {
        float ts = rs[0] + rs[1] + rs[2] + rs[3];
        float ts2 = rs2[0] + rs2[1] + rs2[2] + rs2[3];
        float m = ts / D_HID;
        mv[0] = m; mv[1] = rsqrtf(ts2 / D_HID - m * m + LN_EPS);
    }
    __syncthreads();
    float m = mv[0], r = mv[1];
    x[tid]       = fmaxf((v0 - m) * r * gp[tid]       + bp[tid],       0.f);
    x[tid + 256] = fmaxf((v1 - m) * r * gp[tid + 256] + bp[tid + 256], 0.f);
    x[tid + 512] = fmaxf((v2 - m) * r * gp[tid + 512] + bp[tid + 512], 0.f);
}

// ---------------- LayerNorm+ReLU, W=3072 bf16 (vectorized) ----------------
__global__ __launch_bounds__(256) void k_ln3072_bf16(
    unsigned short* __restrict__ Xb, const float* __restrict__ g, const float* __restrict__ b,
    const unsigned* __restrict__ eos, const unsigned* __restrict__ totp) {
    const int row = blockIdx.x;
    if ((unsigned)row >= *totp) return;
    const unsigned e = eos[row];
    const float* gp = g + (size_t)e * FFN_DIM;
    const float* bp = b + (size_t)e * FFN_DIM;
    unsigned short* x = Xb + (size_t)row * FFN_DIM;
    const int tid = threadIdx.x;
    float f[12];
    #pragma unroll
    for (int i = 0; i < 3; ++i) {
        ushort4 u = *reinterpret_cast<const ushort4*>(x + (i * 256 + tid) * 4);
        f[i * 4 + 0] = bf2f(u.x); f[i * 4 + 1] = bf2f(u.y);
        f[i * 4 + 2] = bf2f(u.z); f[i * 4 + 3] = bf2f(u.w);
    }
    float s = 0.f, s2 = 0.f;
    #pragma unroll
    for (int i = 0; i < 12; ++i) { s += f[i]; s2 += f[i] * f[i]; }
    __shared__ float rs[4], rs2[4], mv[2];
    #pragma unroll
    for (int o = 32; o > 0; o >>= 1) { s += __shfl_down(s, o); s2 += __shfl_down(s2, o); }
    const int wv = tid >> 6, ln = tid & 63;
    if (ln == 0) { rs[wv] = s; rs2[wv] = s2; }
    __syncthreads();
    if (tid == 0) {
        float ts = rs[0] + rs[1] + rs[2] + rs[3];
        float ts2 = rs2[0] + rs2[1] + rs2[2] + rs2[3];
        float m = ts / FFN_DIM;
        mv[0] = m; mv[1] = rsqrtf(ts2 / FFN_DIM - m * m + LN_EPS);
    }
    __syncthreads();
    float m = mv[0], r = mv[1];
    #pragma unroll
    for (int i = 0; i < 3; ++i) {
        int off = (i * 256 + tid) * 4;
        float4 gg = *reinterpret_cast<const float4*>(gp + off);
        float4 bb = *reinterpret_cast<const float4*>(bp + off);
        ushort4 o;
        o.x = f2bf_rn(fmaxf((f[i * 4 + 0] - m) * r * gg.x + bb.x, 0.f));
        o.y = f2bf_rn(fmaxf((f[i * 4 + 1] - m) * r * gg.y + bb.y, 0.f));
        o.z = f2bf_rn(fmaxf((f[i * 4 + 2] - m) * r * gg.z + bb.z, 0.f));
        o.w = f2bf_rn(fmaxf((f[i * 4 + 3] - m) * r * gg.w + bb.w, 0.f));
        *reinterpret_cast<ushort4*>(x + off) = o;
    }
}

// ---------------- router: logits, softmax, top-2, losses, counts (fp32) ----------------
__global__ __launch_bounds__(256) void k_router(
    const float* __restrict__ HR, const float* __restrict__ RW2, const float* __restrict__ RB2,
    unsigned* __restrict__ toke, float* __restrict__ tokw,
    unsigned* __restrict__ counts, float* __restrict__ zsum, float* __restrict__ loadsum) {
    const int wv = threadIdx.x >> 6, ln = threadIdx.x & 63;
    const int t = blockIdx.x * 4 + wv;
    __shared__ float part[4][64][9];
    float p[NE] = {};
    const float* hrow = HR + (size_t)t * D_HID;
    for (int k = ln; k < D_HID; k += 64) {
        float h = hrow[k];
        const float* w = RW2 + (size_t)k * NE;
        #pragma unroll
        for (int j = 0; j < NE; ++j) p[j] += h * w[j];
    }
    #pragma unroll
    for (int j = 0; j < NE; ++j) part[wv][ln][j] = p[j];
    __syncthreads();
    if (ln < NE) {
        float sj = 0.f;
        for (int l = 0; l < 64; ++l) sj += part[wv][l][ln];
        part[wv][0][ln] = sj + RB2[ln];
    }
    __syncthreads();
    if (ln == 0) {
        float lg[NE];
        #pragma unroll
        for (int j = 0; j < NE; ++j) lg[j] = part[wv][0][j];
        float mx = lg[0];
        #pragma unroll
        for (int j = 1; j < NE; ++j) mx = fmaxf(mx, lg[j]);
        float ex[NE], se = 0.f;
        #pragma unroll
        for (int j = 0; j < NE; ++j) { ex[j] = expf(lg[j] - mx); se += ex[j]; }
        float lse = logf(se) + mx;
        atomicAdd(zsum, lse * lse);
        int i0 = 0;
        #pragma unroll
        for (int j = 1; j < NE; ++j) if (ex[j] > ex[i0]) i0 = j;
        int i1 = (i0 == 0) ? 1 : 0;
        #pragma unroll
        for (int j = 0; j < NE; ++j) if (j != i0 && ex[j] > ex[i1]) i1 = j;
        float w0 = ex[i0] / (ex[i0] + ex[i1]);
        float w1 = 1.0f - w0;
        toke[t * 2 + 0] = (unsigned)i0; toke[t * 2 + 1] = (unsigned)i1;
        tokw[t * 2 + 0] = w0;           tokw[t * 2 + 1] = w1;
        atomicAdd(&counts[i0], 1u); atomicAdd(&counts[i1], 1u);
        atomicAdd(&loadsum[i0], w0); atomicAdd(&loadsum[i1], w1);
    }
}

// ---------------- prefix with 16-padding + pad-slot fill ----------------
__global__ void k_prefix(const unsigned* __restrict__ counts, unsigned* __restrict__ offs,
                         unsigned* __restrict__ cntp, unsigned* __restrict__ totp,
                         unsigned* __restrict__ tokv, unsigned* __restrict__ eosv,
                         float* __restrict__ wslot) {
    if (threadIdx.x == 0) {
        unsigned o = 0;
        for (int e = 0; e < NE; ++e) {
            unsigned c = counts[e];
            unsigned cp = (c + 15u) & ~15u;
            offs[e] = o; cntp[e] = cp;
            for (unsigned i = c; i < cp; ++i) {
                unsigned s = o + i;
                tokv[s] = 0u; eosv[s] = (unsigned)e; wslot[s] = 0.0f;
            }
            o += cp;
        }
        totp[0] = o;
    }
}

__global__ void k_scatter(const unsigned* __restrict__ toke, const float* __restrict__ tokw,
                          const unsigned* __restrict__ offs, unsigned* __restrict__ cursors,
                          unsigned* __restrict__ tokv, unsigned* __restrict__ eosv,
                          float* __restrict__ wslot) {
    int t = blockIdx.x * 256 + threadIdx.x;
    if (t >= T_TOK) return;
    #pragma unroll
    for (int k = 0; k < 2; ++k) {
        unsigned e = toke[t * 2 + k];
        unsigned slot = offs[e] + atomicAdd(&cursors[e], 1u);
        tokv[slot] = (unsigned)t;
        eosv[slot] = e;
        wslot[slot] = tokw[t * 2 + k];
    }
}

// ======== grouped GEMM1: gathered x(f32->bf16) @ split-bf16 ew1 -> h1(bf16) ========
// tile 128x128, BK=32; 1D grid 12288 XCD-swizzled: chunk = one expert, x-major
__global__ __launch_bounds__(256) void k_gemm1_mfma(
    const float* __restrict__ X, const float* __restrict__ EW1, const float* __restrict__ EB1,
    const unsigned* __restrict__ tokv, const unsigned* __restrict__ offs,
    const unsigned* __restrict__ cntp, unsigned short* __restrict__ H1) {
    const int bid = blockIdx.x;
    const int lid = (bid & 7) * 1536 + (bid >> 3);     // 12288 = 8 * 1536
    const int e = lid / 1536, rgrp = lid % 1536;
    const int m0 = (rgrp / 24) * 128, n0 = (rgrp % 24) * 128;
    const unsigned cp = cntp[e];
    if ((unsigned)m0 >= cp) return;
    const unsigned base = offs[e];
    const float* __restrict__ W = EW1 + (size_t)e * D_HID * FFN_DIM;
    __shared__ unsigned short As[128][40];
    __shared__ unsigned short Bh[128][40];
    __shared__ unsigned short Bl[128][40];
    __shared__ unsigned stok[128];
    const int tid = threadIdx.x;
    if (tid < 128) {
        unsigned rr = (unsigned)(m0 + tid);
        stok[tid] = tokv[base + ((rr < cp) ? rr : (cp - 1u))];
    }
    __syncthreads();
    const int wv = tid >> 6, ln = tid & 63;
    const int m_off = (wv >> 1) * 64, n_off = (wv & 1) * 64;
    const int lrow = ln & 15, lkg = ln >> 4;
    const int ar = tid >> 1, ahf = (tid & 1) * 16;
    const int bn = tid & 127, bq = tid >> 7;
    f32x4 acc[4][4] = {};
    const float* aptr = X + (size_t)stok[ar] * D_HID + ahf;
    for (int k0 = 0; k0 < D_HID; k0 += 32) {
        {   // A: fp32 -> bf16
            unsigned short th[16];
            #pragma unroll
            for (int q = 0; q < 4; ++q) {
                float4 v = *reinterpret_cast<const float4*>(aptr + k0 + q * 4);
                th[q * 4 + 0] = f2bf_rn(v.x); th[q * 4 + 1] = f2bf_rn(v.y);
                th[q * 4 + 2] = f2bf_rn(v.z); th[q * 4 + 3] = f2bf_rn(v.w);
            }
            *reinterpret_cast<uint4*>(&As[ar][ahf])     = *reinterpret_cast<uint4*>(&th[0]);
            *reinterpret_cast<uint4*>(&As[ar][ahf + 8]) = *reinterpret_cast<uint4*>(&th[8]);
        }
        {   // B: coalesced loads, register convert, b128 writes
            const float* wsrc = W + (size_t)(k0 + bq * 16) * FFN_DIM + n0 + bn;
            unsigned short th[16], tl[16];
            #pragma unroll
            for (int kk = 0; kk < 16; ++kk) {
                float f = wsrc[(size_t)kk * FFN_DIM];
                float hf = bfround(f);
                th[kk] = f2bf_rn(f);
                tl[kk] = f2bf_rn(f - hf);
            }
            *reinterpret_cast<uint4*>(&Bh[bn][bq * 16])     = *reinterpret_cast<uint4*>(&th[0]);
            *reinterpret_cast<uint4*>(&Bh[bn][bq * 16 + 8]) = *reinterpret_cast<uint4*>(&th[8]);
            *reinterpret_cast<uint4*>(&Bl[bn][bq * 16])     = *reinterpret_cast<uint4*>(&tl[0]);
            *reinterpret_cast<uint4*>(&Bl[bn][bq * 16 + 8]) = *reinterpret_cast<uint4*>(&tl[8]);
        }
        __syncthreads();
        bf16x8 a[4];
        #pragma unroll
        for (int i = 0; i < 4; ++i)
            a[i] = *reinterpret_cast<const bf16x8*>(&As[m_off + i * 16 + lrow][lkg * 8]);
        #pragma unroll
        for (int j = 0; j < 4; ++j) {
            bf16x8 b_h = *reinterpret_cast<const bf16x8*>(&Bh[n_off + j * 16 + lrow][lkg * 8]);
            bf16x8 b_l = *reinterpret_cast<const bf16x8*>(&Bl[n_off + j * 16 + lrow][lkg * 8]);
            #pragma unroll
            for (int i = 0; i < 4; ++i) {
                acc[i][j] = __builtin_amdgcn_mfma_f32_16x16x32_bf16(a[i], b_h, acc[i][j], 0, 0, 0);
                acc[i][j] = __builtin_amdgcn_mfma_f32_16x16x32_bf16(a[i], b_l, acc[i][j], 0, 0, 0);
            }
        }
        __syncthreads();
    }
    const float* bias = EB1 + (size_t)e * FFN_DIM + n0;
    #pragma unroll
    for (int i = 0; i < 4; ++i)
        #pragma unroll
        for (int r = 0; r < 4; ++r) {
            unsigned rr = (unsigned)(m0 + m_off + i * 16 + lkg * 4 + r);
            if (rr < cp) {
                unsigned short* dst = H1 + (size_t)(base + rr) * FFN_DIM + n0;
                #pragma unroll
                for (int j = 0; j < 4; ++j) {
                    int c = n_off + j * 16 + lrow;
                    dst[c] = f2bf_rn(acc[i][j][r] + bias[c]);
                }
            }
        }
}

// ======== grouped GEMM2: h1(bf16) @ split-bf16 ew2 -> h2(f32) ========
// 1D grid 3072 XCD-swizzled: chunk = one expert, x-major
__global__ __launch_bounds__(256) void k_gemm2_mfma(
    const unsigned short* __restrict__ H1, const float* __restrict__ EW2,
    const float* __restrict__ EB2, const unsigned* __restrict__ offs,
    const unsigned* __restrict__ cntp, float* __restrict__ H2) {
    const int bid = blockIdx.x;
    const int lid = (bid & 7) * 384 + (bid >> 3);      // 3072 = 8 * 384
    const int e = lid / 384, rgrp = lid % 384;
    const int m0 = (rgrp / 6) * 128, n0 = (rgrp % 6) * 128;
    const unsigned cp = cntp[e];
    if ((unsigned)m0 >= cp) return;
    const unsigned base = offs[e];
    const float* __restrict__ W = EW2 + (size_t)e * FFN_DIM * D_HID;
    __shared__ unsigned short As[128][40];
    __shared__ unsigned short Bh[128][40];
    __shared__ unsigned short Bl[128][40];
    const int tid = threadIdx.x;
    const int wv = tid >> 6, ln = tid & 63;
    const int m_off = (wv >> 1) * 64, n_off = (wv & 1) * 64;
    const int lrow = ln & 15, lkg = ln >> 4;
    const int ar = tid >> 1, ahf = (tid & 1) * 16;
    const int bn = tid & 127, bq = tid >> 7;
    unsigned arow = (unsigned)(m0 + ar);
    if (arow >= cp) arow = cp - 1u;
    const unsigned short* aptr = H1 + (size_t)(base + arow) * FFN_DIM + ahf;
    f32x4 acc[4][4] = {};
    for (int k0 = 0; k0 < FFN_DIM; k0 += 32) {
        {   // A: bf16 direct b128 copies
            *reinterpret_cast<uint4*>(&As[ar][ahf])     = *reinterpret_cast<const uint4*>(aptr + k0);
            *reinterpret_cast<uint4*>(&As[ar][ahf + 8]) = *reinterpret_cast<const uint4*>(aptr + k0 + 8);
        }
        {   // B: coalesced loads, register convert, b128 writes
            const float* wsrc = W + (size_t)(k0 + bq * 16) * D_HID + n0 + bn;
            unsigned short th[16], tl[16];
            #pragma unroll
            for (int kk = 0; kk < 16; ++kk) {
                float f = wsrc[(size_t)kk * D_HID];
                float hf = bfround(f);
                th[kk] = f2bf_rn(f);
                tl[kk] = f2bf_rn(f - hf);
            }
            *reinterpret_cast<uint4*>(&Bh[bn][bq * 16])     = *reinterpret_cast<uint4*>(&th[0]);
            *reinterpret_cast<uint4*>(&Bh[bn][bq * 16 + 8]) = *reinterpret_cast<uint4*>(&th[8]);
            *reinterpret_cast<uint4*>(&Bl[bn][bq * 16])     = *reinterpret_cast<uint4*>(&tl[0]);
            *reinterpret_cast<uint4*>(&Bl[bn][bq * 16 + 8]) = *reinterpret_cast<uint4*>(&tl[8]);
        }
        __syncthreads();
        bf16x8 a[4];
        #pragma unroll
        for (int i = 0; i < 4; ++i)
            a[i] = *reinterpret_cast<const bf16x8*>(&As[m_off + i * 16 + lrow][lkg * 8]);
        #pragma unroll
        for (int j = 0; j < 4; ++j) {
            bf16x8 b_h = *reinterpret_cast<const bf16x8*>(&Bh[n_off + j * 16 + lrow][lkg * 8]);
            bf16x8 b_l = *reinterpret_cast<const bf16x8*>(&Bl[n_off + j * 16 + lrow][lkg * 8]);
            #pragma unroll
            for (int i = 0; i < 4; ++i) {
                acc[i][j] = __builtin_amdgcn_mfma_f32_16x16x32_bf16(a[i], b_h, acc[i][j], 0, 0, 0);
                acc[i][j] = __builtin_amdgcn_mfma_f32_16x16x32_bf16(a[i], b_l, acc[i][j], 0, 0, 0);
            }
        }
        __syncthreads();
    }
    const float* bias = EB2 + (size_t)e * D_HID + n0;
    #pragma unroll
    for (int i = 0; i < 4; ++i)
        #pragma unroll
        for (int r = 0; r < 4; ++r) {
            unsigned rr = (unsigned)(m0 + m_off + i * 16 + lkg * 4 + r);
            if (rr < cp) {
                float* dst = H2 + (size_t)(base + rr) * D_HID + n0;
                #pragma unroll
                for (int j = 0; j < 4; ++j) {
                    int c = n_off + j * 16 + lrow;
                    dst[c] = acc[i][j][r] + bias[c];
                }
            }
        }
}

// ---------------- GEMM3 batched 16 slots/block + weighted scatter ----------------
__global__ __launch_bounds__(256) void k_gemm3b(
    const float* __restrict__ H2, const float* __restrict__ EW3, const float* __restrict__ EB3,
    const unsigned* __restrict__ tokv, const unsigned* __restrict__ eosv,
    const float* __restrict__ wslot, const unsigned* __restrict__ totp,
    float* __restrict__ out) {
    const int s0 = blockIdx.x * 16;
    if ((unsigned)s0 >= *totp) return;
    __shared__ float sh[16][D_HID];
    const int tid = threadIdx.x;
    #pragma unroll
    for (int s = 0; s < 16; ++s) {
        const float* h = H2 + (size_t)(s0 + s) * D_HID;
        sh[s][tid] = h[tid]; sh[s][tid + 256] = h[tid + 256]; sh[s][tid + 512] = h[tid + 512];
    }
    const unsigned e = eosv[s0];   // uniform within block (16-padded expert ranges)
    __syncthreads();
    if (tid < NCLS) {
        float acc[16];
        float bias = EB3[e * NCLS + tid];
        #pragma unroll
        for (int s = 0; s < 16; ++s) acc[s] = bias;
        const float* w3 = EW3 + (size_t)e * D_HID * NCLS + tid;
        #pragma unroll 4
        for (int k = 0; k < D_HID; ++k) {
            float wv = w3[(size_t)k * NCLS];
            #pragma unroll
            for (int s = 0; s < 16; ++s) acc[s] = fmaf(sh[s][k], wv, acc[s]);
        }
        #pragma unroll
        for (int s = 0; s < 16; ++s) {
            float w = wslot[s0 + s] * (1.0f / NSEQ);
            if (w != 0.0f) {
                unsigned b = tokv[s0 + s] >> 5;
                atomicAdd(&out[b * NCLS + tid], w * acc[s]);
            }
        }
    }
}

__global__ void k_aux(const float* __restrict__ zsum, const float* __restrict__ loadsum,
                      float* __restrict__ out) {
    if (threadIdx.x == 0) {
        float z = 0.1f * zsum[0] / (float)T_TOK;
        float lb = 0.f;
        for (int e = 0; e < NE; ++e) {
            float d = loadsum[e] / (float)T_TOK - 0.125f;
            lb += d * d;
        }
        out[OUT_N] = z + 0.1f * lb;
    }
}

extern "C" void kernel_launch(void* const* d_in, const int* in_sizes, int n_in,
                              void* d_out, int out_size, void* d_ws, size_t ws_size,
                              hipStream_t stream) {
    (void)in_sizes; (void)n_in; (void)out_size; (void)ws_size;
    const float* x    = (const float*)d_in[0];
    const float* rw1  = (const float*)d_in[1];
    const float* rb1  = (const float*)d_in[2];
    const float* rlg  = (const float*)d_in[3];
    const float* rlb  = (const float*)d_in[4];
    const float* rw2  = (const float*)d_in[5];
    const float* rb2  = (const float*)d_in[6];
    const float* ew1  = (const float*)d_in[7];
    const float* eb1  = (const float*)d_in[8];
    const float* el1g = (const float*)d_in[9];
    const float* el1b = (const float*)d_in[10];
    const float* ew2  = (const float*)d_in[11];
    const float* eb2  = (const float*)d_in[12];
    const float* el2g = (const float*)d_in[13];
    const float* el2b = (const float*)d_in[14];
    const float* ew3  = (const float*)d_in[15];
    const float* eb3  = (const float*)d_in[16];
    float* out = (float*)d_out;

    uint8_t* ws = (uint8_t*)d_ws;
    // [0, 50.72MB): h2 (16512x768 f32); hr (8192x768 f32) overlaps (hr dead before h2 written)
    float* hr = (float*)ws;
    float* h2 = (float*)ws;
    unsigned short* h1 = (unsigned short*)(ws + (size_t)50724864);   // 16512x3072 bf16
    uint8_t* sb = ws + (size_t)152174592;
    unsigned* tokv   = (unsigned*)sb;               // [NSLOTP]
    unsigned* eosv   = tokv + NSLOTP;               // [NSLOTP]
    float*    wslot  = (float*)(eosv + NSLOTP);     // [NSLOTP]
    unsigned* toke   = (unsigned*)(wslot + NSLOTP); // [T*2]
    float*    tokw   = (float*)(toke + NSLOT);      // [T*2]
    unsigned* counts = (unsigned*)(tokw + NSLOT);   // [8]
    unsigned* cursors = counts + NE;                // [8]
    unsigned* offs    = cursors + NE;               // [8]
    unsigned* cntp    = offs + NE;                  // [8]
    unsigned* totp    = cntp + NE;                  // [1]
    float*    zsum    = (float*)(totp + 1);         // [1]
    float*    loadsum = zsum + 1;                   // [8]

    k_zero<<<dim3(192), dim3(256), 0, stream>>>(out, counts, cursors, zsum, loadsum);
    k_rgemm_mfma<<<dim3(384), dim3(256), 0, stream>>>(x, rw1, rb1, hr);
    k_ln768_f32<<<dim3(T_TOK), dim3(256), 0, stream>>>(hr, rlg, rlb, nullptr, nullptr);
    k_router<<<dim3(T_TOK / 4), dim3(256), 0, stream>>>(
        hr, rw2, rb2, toke, tokw, counts, zsum, loadsum);
    k_prefix<<<dim3(1), dim3(64), 0, stream>>>(counts, offs, cntp, totp, tokv, eosv, wslot);
    k_scatter<<<dim3(T_TOK / 256), dim3(256), 0, stream>>>(
        toke, tokw, offs, cursors, tokv, eosv, wslot);
    k_gemm1_mfma<<<dim3(12288), dim3(256), 0, stream>>>(
        x, ew1, eb1, tokv, offs, cntp, h1);
    k_ln3072_bf16<<<dim3(NSLOTP), dim3(256), 0, stream>>>(h1, el1g, el1b, eosv, totp);
    k_gemm2_mfma<<<dim3(3072), dim3(256), 0, stream>>>(
        h1, ew2, eb2, offs, cntp, h2);
    k_ln768_f32<<<dim3(NSLOTP), dim3(256), 0, stream>>>(h2, el2g, el2b, eosv, totp);
    k_gemm3b<<<dim3(NSLOTP / 16), dim3(256), 0, stream>>>(
        h2, ew3, eb3, tokv, eosv, wslot, totp, out);
    k_aux<<<dim3(1), dim3(64), 0, stream>>>(zsum, loadsum, out);
}

// Round 6
// 1411.507 us; speedup vs baseline: 1.5438x; 1.2298x over previous
//
#include <hip/hip_runtime.h>
#include <hip/hip_bf16.h>
#include <stdint.h>

#define T_TOK   8192
#define D_HID   768
#define NE      8
#define FFN_DIM 3072
#define NCLS    191
#define NSEQ    32
#define NSLOT   (T_TOK * 2)
#define NSLOTP  (NSLOT + 128)
#define LN_EPS  1e-5f
#define OUT_N   (256 * NCLS)   // 48896 logits + 1 aux

typedef __bf16 bf16x8 __attribute__((ext_vector_type(8)));
typedef float  f32x4  __attribute__((ext_vector_type(4)));

static __device__ __forceinline__ float bf2f(unsigned short u) {
    return __uint_as_float(((unsigned)u) << 16);
}
static __device__ __forceinline__ unsigned short f2bf(float f) {
    return __builtin_bit_cast(unsigned short, (__bf16)f);
}
static __device__ __forceinline__ float bfround(float f) {
    return (float)((__bf16)f);
}

// ---------------- init ----------------
__global__ void k_zero(float* __restrict__ out, unsigned* __restrict__ counts,
                       unsigned* __restrict__ cursors, float* __restrict__ zsum,
                       float* __restrict__ loadsum) {
    int i = blockIdx.x * 256 + threadIdx.x;
    if (i < OUT_N + 1) out[i] = 0.0f;
    if (i < NE) { counts[i] = 0u; cursors[i] = 0u; loadsum[i] = 0.0f; }
    if (i == 0) zsum[0] = 0.0f;
}

// ---------------- fused pre-convert: X->bf16, rw1->[n][k] hi/lo, ew3->[c][k] hi/lo ----------------
__global__ __launch_bounds__(256) void k_prep(
    const float* __restrict__ X, const float* __restrict__ RW1, const float* __restrict__ EW3,
    unsigned short* __restrict__ Xb, unsigned short* __restrict__ RW1h,
    unsigned short* __restrict__ RW1l, unsigned short* __restrict__ W3h,
    unsigned short* __restrict__ W3l) {
    const int bid = blockIdx.x, tid = threadIdx.x;
    if (bid < 3072) {
        size_t i0 = (size_t)bid * 2048 + (size_t)tid * 8;
        float4 a = *reinterpret_cast<const float4*>(X + i0);
        float4 b = *reinterpret_cast<const float4*>(X + i0 + 4);
        unsigned short t[8] = {f2bf(a.x), f2bf(a.y), f2bf(a.z), f2bf(a.w),
                               f2bf(b.x), f2bf(b.y), f2bf(b.z), f2bf(b.w)};
        *reinterpret_cast<uint4*>(Xb + i0) = *reinterpret_cast<uint4*>(t);
        return;
    }
    __shared__ float tile[64][65];
    const int rr = tid >> 2, c4 = (tid & 3) * 16;
    if (bid < 3216) {       // rw1 [k][n] -> [n][k]
        int t = bid - 3072, kt = t / 12, nt = t % 12;
        const float* src = RW1 + (size_t)(kt * 64 + rr) * D_HID + nt * 64 + c4;
        #pragma unroll
        for (int q = 0; q < 4; ++q) {
            float4 v = *reinterpret_cast<const float4*>(src + q * 4);
            tile[rr][c4 + q * 4 + 0] = v.x; tile[rr][c4 + q * 4 + 1] = v.y;
            tile[rr][c4 + q * 4 + 2] = v.z; tile[rr][c4 + q * 4 + 3] = v.w;
        }
        __syncthreads();
        unsigned short th[16], tl[16];
        #pragma unroll
        for (int j = 0; j < 16; ++j) {
            float f = tile[c4 + j][rr];
            th[j] = f2bf(f); tl[j] = f2bf(f - bfround(f));
        }
        size_t o = (size_t)(nt * 64 + rr) * D_HID + kt * 64 + c4;
        *reinterpret_cast<uint4*>(RW1h + o)     = *reinterpret_cast<uint4*>(&th[0]);
        *reinterpret_cast<uint4*>(RW1h + o + 8) = *reinterpret_cast<uint4*>(&th[8]);
        *reinterpret_cast<uint4*>(RW1l + o)     = *reinterpret_cast<uint4*>(&tl[0]);
        *reinterpret_cast<uint4*>(RW1l + o + 8) = *reinterpret_cast<uint4*>(&tl[8]);
    } else {                // ew3 [e][k][c] -> [e][c(192)][k]
        int t = bid - 3216, e = t / 36, s = t % 36, kt = s / 3, ct = s % 3;
        const float* src = EW3 + (size_t)e * D_HID * NCLS + (size_t)(kt * 64 + rr) * NCLS;
        #pragma unroll
        for (int j = 0; j < 16; ++j) {
            int c = ct * 64 + c4 + j;
            tile[rr][c4 + j] = (c < NCLS) ? src[c] : 0.0f;
        }
        __syncthreads();
        unsigned short th[16], tl[16];
        #pragma unroll
        for (int j = 0; j < 16; ++j) {
            float f = tile[c4 + j][rr];
            th[j] = f2bf(f); tl[j] = f2bf(f - bfround(f));
        }
        size_t o = (size_t)(e * 192 + ct * 64 + rr) * D_HID + kt * 64 + c4;
        *reinterpret_cast<uint4*>(W3h + o)     = *reinterpret_cast<uint4*>(&th[0]);
        *reinterpret_cast<uint4*>(W3h + o + 8) = *reinterpret_cast<uint4*>(&th[8]);
        *reinterpret_cast<uint4*>(W3l + o)     = *reinterpret_cast<uint4*>(&tl[0]);
        *reinterpret_cast<uint4*>(W3l + o + 8) = *reinterpret_cast<uint4*>(&tl[8]);
    }
}

// ======== router GEMM1: split-A x split-B MFMA (fp32-grade for exact top-2) ========
__global__ __launch_bounds__(256) void k_rgemm(
    const float* __restrict__ X, const unsigned short* __restrict__ RW1h,
    const unsigned short* __restrict__ RW1l, const float* __restrict__ bias,
    float* __restrict__ C) {
    const int bid = blockIdx.x;
    const int lid = (bid & 7) * 48 + (bid >> 3);
    const int m0 = (lid / 6) * 128, n0 = (lid % 6) * 128;
    __shared__ unsigned short Ah[128][40], Al[128][40], Bh[128][40], Bl[128][40];
    const int tid = threadIdx.x;
    const int wv = tid >> 6, ln = tid & 63;
    const int m_off = (wv >> 1) * 64, n_off = (wv & 1) * 64;
    const int lrow = ln & 15, lkg = ln >> 4;
    const int ar = tid >> 1, ac = (tid & 1) * 16;
    const float* aptr = X + (size_t)(m0 + ar) * D_HID + ac;
    const unsigned short* bph = RW1h + (size_t)(n0 + ar) * D_HID + ac;
    const unsigned short* bpl = RW1l + (size_t)(n0 + ar) * D_HID + ac;
    f32x4 acc[4][4] = {};
    for (int k0 = 0; k0 < D_HID; k0 += 32) {
        unsigned short th[16], tl[16];
        #pragma unroll
        for (int q = 0; q < 4; ++q) {
            float4 v = *reinterpret_cast<const float4*>(aptr + k0 + q * 4);
            float fv[4] = {v.x, v.y, v.z, v.w};
            #pragma unroll
            for (int j = 0; j < 4; ++j) {
                th[q * 4 + j] = f2bf(fv[j]);
                tl[q * 4 + j] = f2bf(fv[j] - bfround(fv[j]));
            }
        }
        *reinterpret_cast<uint4*>(&Ah[ar][ac])     = *reinterpret_cast<uint4*>(&th[0]);
        *reinterpret_cast<uint4*>(&Ah[ar][ac + 8]) = *reinterpret_cast<uint4*>(&th[8]);
        *reinterpret_cast<uint4*>(&Al[ar][ac])     = *reinterpret_cast<uint4*>(&tl[0]);
        *reinterpret_cast<uint4*>(&Al[ar][ac + 8]) = *reinterpret_cast<uint4*>(&tl[8]);
        *reinterpret_cast<uint4*>(&Bh[ar][ac])     = *reinterpret_cast<const uint4*>(bph + k0);
        *reinterpret_cast<uint4*>(&Bh[ar][ac + 8]) = *reinterpret_cast<const uint4*>(bph + k0 + 8);
        *reinterpret_cast<uint4*>(&Bl[ar][ac])     = *reinterpret_cast<const uint4*>(bpl + k0);
        *reinterpret_cast<uint4*>(&Bl[ar][ac + 8]) = *reinterpret_cast<const uint4*>(bpl + k0 + 8);
        __syncthreads();
        bf16x8 a_h[4], a_l[4];
        #pragma unroll
        for (int i = 0; i < 4; ++i) {
            a_h[i] = *reinterpret_cast<const bf16x8*>(&Ah[m_off + i * 16 + lrow][lkg * 8]);
            a_l[i] = *reinterpret_cast<const bf16x8*>(&Al[m_off + i * 16 + lrow][lkg * 8]);
        }
        #pragma unroll
        for (int j = 0; j < 4; ++j) {
            bf16x8 b_h = *reinterpret_cast<const bf16x8*>(&Bh[n_off + j * 16 + lrow][lkg * 8]);
            bf16x8 b_l = *reinterpret_cast<const bf16x8*>(&Bl[n_off + j * 16 + lrow][lkg * 8]);
            #pragma unroll
            for (int i = 0; i < 4; ++i) {
                acc[i][j] = __builtin_amdgcn_mfma_f32_16x16x32_bf16(a_h[i], b_h, acc[i][j], 0, 0, 0);
                acc[i][j] = __builtin_amdgcn_mfma_f32_16x16x32_bf16(a_h[i], b_l, acc[i][j], 0, 0, 0);
                acc[i][j] = __builtin_amdgcn_mfma_f32_16x16x32_bf16(a_l[i], b_h, acc[i][j], 0, 0, 0);
            }
        }
        __syncthreads();
    }
    #pragma unroll
    for (int i = 0; i < 4; ++i)
        #pragma unroll
        for (int r = 0; r < 4; ++r) {
            int row = m0 + m_off + i * 16 + lkg * 4 + r;
            float* dst = C + (size_t)row * D_HID;
            #pragma unroll
            for (int j = 0; j < 4; ++j) {
                int c = n0 + n_off + j * 16 + lrow;
                dst[c] = acc[i][j][r] + bias[c];
            }
        }
}

// ---------------- LayerNorm+ReLU, W=768 fp32 (router hidden) ----------------
__global__ __launch_bounds__(256) void k_ln768_f32(
    float* __restrict__ Xb, const float* __restrict__ g, const float* __restrict__ b) {
    const int row = blockIdx.x;
    float* x = Xb + (size_t)row * D_HID;
    const int tid = threadIdx.x;
    float v0 = x[tid], v1 = x[tid + 256], v2 = x[tid + 512];
    float s = v0 + v1 + v2, s2 = v0 * v0 + v1 * v1 + v2 * v2;
    __shared__ float rs[4], rs2[4], mv[2];
    #pragma unroll
    for (int o = 32; o > 0; o >>= 1) { s += __shfl_down(s, o); s2 += __shfl_down(s2, o); }
    const int wv = tid >> 6, ln = tid & 63;
    if (ln == 0) { rs[wv] = s; rs2[wv] = s2; }
    __syncthreads();
    if (tid == 0) {
        float ts = rs[0] + rs[1] + rs[2] + rs[3];
        float ts2 = rs2[0] + rs2[1] + rs2[2] + rs2[3];
        float m = ts / D_HID;
        mv[0] = m; mv[1] = rsqrtf(ts2 / D_HID - m * m + LN_EPS);
    }
    __syncthreads();
    float m = mv[0], r = mv[1];
    x[tid]       = fmaxf((v0 - m) * r * g[tid]       + b[tid],       0.f);
    x[tid + 256] = fmaxf((v1 - m) * r * g[tid + 256] + b[tid + 256], 0.f);
    x[tid + 512] = fmaxf((v2 - m) * r * g[tid + 512] + b[tid + 512], 0.f);
}

// ---------------- LayerNorm+ReLU, W=768 bf16 in-place (h2) ----------------
__global__ __launch_bounds__(256) void k_ln768_bf16(
    unsigned short* __restrict__ Xb, const float* __restrict__ g, const float* __restrict__ b,
    const unsigned* __restrict__ eos, const unsigned* __restrict__ totp) {
    const int row = blockIdx.x;
    if ((unsigned)row >= *totp) return;
    const unsigned e = eos[row];
    const float* gp = g + (size_t)e * D_HID;
    const float* bp = b + (size_t)e * D_HID;
    unsigned short* x = Xb + (size_t)row * D_HID;
    const int tid = threadIdx.x;
    float f[4] = {0.f, 0.f, 0.f, 0.f};
    if (tid < 192) {
        ushort4 u = *reinterpret_cast<const ushort4*>(x + tid * 4);
        f[0] = bf2f(u.x); f[1] = bf2f(u.y); f[2] = bf2f(u.z); f[3] = bf2f(u.w);
    }
    float s = f[0] + f[1] + f[2] + f[3];
    float s2 = f[0] * f[0] + f[1] * f[1] + f[2] * f[2] + f[3] * f[3];
    __shared__ float rs[4], rs2[4], mv[2];
    #pragma unroll
    for (int o = 32; o > 0; o >>= 1) { s += __shfl_down(s, o); s2 += __shfl_down(s2, o); }
    const int wv = tid >> 6, ln = tid & 63;
    if (ln == 0) { rs[wv] = s; rs2[wv] = s2; }
    __syncthreads();
    if (tid == 0) {
        float ts = rs[0] + rs[1] + rs[2] + rs[3];
        float ts2 = rs2[0] + rs2[1] + rs2[2] + rs2[3];
        float m = ts / D_HID;
        mv[0] = m; mv[1] = rsqrtf(ts2 / D_HID - m * m + LN_EPS);
    }
    __syncthreads();
    if (tid < 192) {
        float m = mv[0], r = mv[1];
        float4 gg = *reinterpret_cast<const float4*>(gp + tid * 4);
        float4 bb = *reinterpret_cast<const float4*>(bp + tid * 4);
        ushort4 o;
        o.x = f2bf(fmaxf((f[0] - m) * r * gg.x + bb.x, 0.f));
        o.y = f2bf(fmaxf((f[1] - m) * r * gg.y + bb.y, 0.f));
        o.z = f2bf(fmaxf((f[2] - m) * r * gg.z + bb.z, 0.f));
        o.w = f2bf(fmaxf((f[3] - m) * r * gg.w + bb.w, 0.f));
        *reinterpret_cast<ushort4*>(x + tid * 4) = o;
    }
}

// ---------------- LayerNorm+ReLU, W=3072 bf16 (h1) ----------------
__global__ __launch_bounds__(256) void k_ln3072_bf16(
    unsigned short* __restrict__ Xb, const float* __restrict__ g, const float* __restrict__ b,
    const unsigned* __restrict__ eos, const unsigned* __restrict__ totp) {
    const int row = blockIdx.x;
    if ((unsigned)row >= *totp) return;
    const unsigned e = eos[row];
    const float* gp = g + (size_t)e * FFN_DIM;
    const float* bp = b + (size_t)e * FFN_DIM;
    unsigned short* x = Xb + (size_t)row * FFN_DIM;
    const int tid = threadIdx.x;
    float f[12];
    #pragma unroll
    for (int i = 0; i < 3; ++i) {
        ushort4 u = *reinterpret_cast<const ushort4*>(x + (i * 256 + tid) * 4);
        f[i * 4 + 0] = bf2f(u.x); f[i * 4 + 1] = bf2f(u.y);
        f[i * 4 + 2] = bf2f(u.z); f[i * 4 + 3] = bf2f(u.w);
    }
    float s = 0.f, s2 = 0.f;
    #pragma unroll
    for (int i = 0; i < 12; ++i) { s += f[i]; s2 += f[i] * f[i]; }
    __shared__ float rs[4], rs2[4], mv[2];
    #pragma unroll
    for (int o = 32; o > 0; o >>= 1) { s += __shfl_down(s, o); s2 += __shfl_down(s2, o); }
    const int wv = tid >> 6, ln = tid & 63;
    if (ln == 0) { rs[wv] = s; rs2[wv] = s2; }
    __syncthreads();
    if (tid == 0) {
        float ts = rs[0] + rs[1] + rs[2] + rs[3];
        float ts2 = rs2[0] + rs2[1] + rs2[2] + rs2[3];
        float m = ts / FFN_DIM;
        mv[0] = m; mv[1] = rsqrtf(ts2 / FFN_DIM - m * m + LN_EPS);
    }
    __syncthreads();
    float m = mv[0], r = mv[1];
    #pragma unroll
    for (int i = 0; i < 3; ++i) {
        int off = (i * 256 + tid) * 4;
        float4 gg = *reinterpret_cast<const float4*>(gp + off);
        float4 bb = *reinterpret_cast<const float4*>(bp + off);
        ushort4 o;
        o.x = f2bf(fmaxf((f[i * 4 + 0] - m) * r * gg.x + bb.x, 0.f));
        o.y = f2bf(fmaxf((f[i * 4 + 1] - m) * r * gg.y + bb.y, 0.f));
        o.z = f2bf(fmaxf((f[i * 4 + 2] - m) * r * gg.z + bb.z, 0.f));
        o.w = f2bf(fmaxf((f[i * 4 + 3] - m) * r * gg.w + bb.w, 0.f));
        *reinterpret_cast<ushort4*>(x + off) = o;
    }
}

// ---------------- router: logits, softmax, top-2, losses, counts (fp32) ----------------
__global__ __launch_bounds__(256) void k_router(
    const float* __restrict__ HR, const float* __restrict__ RW2, const float* __restrict__ RB2,
    unsigned* __restrict__ toke, float* __restrict__ tokw,
    unsigned* __restrict__ counts, float* __restrict__ zsum, float* __restrict__ loadsum) {
    const int wv = threadIdx.x >> 6, ln = threadIdx.x & 63;
    const int t = blockIdx.x * 4 + wv;
    __shared__ float part[4][64][9];
    float p[NE] = {};
    const float* hrow = HR + (size_t)t * D_HID;
    for (int k = ln; k < D_HID; k += 64) {
        float h = hrow[k];
        const float* w = RW2 + (size_t)k * NE;
        #pragma unroll
        for (int j = 0; j < NE; ++j) p[j] += h * w[j];
    }
    #pragma unroll
    for (int j = 0; j < NE; ++j) part[wv][ln][j] = p[j];
    __syncthreads();
    if (ln < NE) {
        float sj = 0.f;
        for (int l = 0; l < 64; ++l) sj += part[wv][l][ln];
        part[wv][0][ln] = sj + RB2[ln];
    }
    __syncthreads();
    if (ln == 0) {
        float lg[NE];
        #pragma unroll
        for (int j = 0; j < NE; ++j) lg[j] = part[wv][0][j];
        float mx = lg[0];
        #pragma unroll
        for (int j = 1; j < NE; ++j) mx = fmaxf(mx, lg[j]);
        float ex[NE], se = 0.f;
        #pragma unroll
        for (int j = 0; j < NE; ++j) { ex[j] = expf(lg[j] - mx); se += ex[j]; }
        float lse = logf(se) + mx;
        atomicAdd(zsum, lse * lse);
        int i0 = 0;
        #pragma unroll
        for (int j = 1; j < NE; ++j) if (ex[j] > ex[i0]) i0 = j;
        int i1 = (i0 == 0) ? 1 : 0;
        #pragma unroll
        for (int j = 0; j < NE; ++j) if (j != i0 && ex[j] > ex[i1]) i1 = j;
        float w0 = ex[i0] / (ex[i0] + ex[i1]);
        float w1 = 1.0f - w0;
        toke[t * 2 + 0] = (unsigned)i0; toke[t * 2 + 1] = (unsigned)i1;
        tokw[t * 2 + 0] = w0;           tokw[t * 2 + 1] = w1;
        atomicAdd(&counts[i0], 1u); atomicAdd(&counts[i1], 1u);
        atomicAdd(&loadsum[i0], w0); atomicAdd(&loadsum[i1], w1);
    }
}

// ---------------- prefix with 16-padding + pad-slot fill ----------------
__global__ void k_prefix(const unsigned* __restrict__ counts, unsigned* __restrict__ offs,
                         unsigned* __restrict__ cntp, unsigned* __restrict__ totp,
                         unsigned* __restrict__ tokv, unsigned* __restrict__ eosv,
                         float* __restrict__ wslot) {
    if (threadIdx.x == 0) {
        unsigned o = 0;
        for (int e = 0; e < NE; ++e) {
            unsigned c = counts[e];
            unsigned cp = (c + 15u) & ~15u;
            offs[e] = o; cntp[e] = cp;
            for (unsigned i = c; i < cp; ++i) {
                unsigned s = o + i;
                tokv[s] = 0u; eosv[s] = (unsigned)e; wslot[s] = 0.0f;
            }
            o += cp;
        }
        totp[0] = o;
    }
}

__global__ void k_scatter(const unsigned* __restrict__ toke, const float* __restrict__ tokw,
                          const unsigned* __restrict__ offs, unsigned* __restrict__ cursors,
                          unsigned* __restrict__ tokv, unsigned* __restrict__ eosv,
                          float* __restrict__ wslot) {
    int t = blockIdx.x * 256 + threadIdx.x;
    if (t >= T_TOK) return;
    #pragma unroll
    for (int k = 0; k < 2; ++k) {
        unsigned e = toke[t * 2 + k];
        unsigned slot = offs[e] + atomicAdd(&cursors[e], 1u);
        tokv[slot] = (unsigned)t;
        eosv[slot] = e;
        wslot[slot] = tokw[t * 2 + k];
    }
}

// ======== grouped GEMM1: Xb16 gathered @ bf16(ew1) -> h1 bf16 ========
// tile 128x128, BK=32; grid 12288: e = bid&7 (XCD-pinned), inner 2m x 24n
__global__ __launch_bounds__(256) void k_gemm1(
    const unsigned short* __restrict__ Xb, const float* __restrict__ EW1,
    const float* __restrict__ EB1, const unsigned* __restrict__ tokv,
    const unsigned* __restrict__ offs, const unsigned* __restrict__ cntp,
    unsigned short* __restrict__ H1) {
    const int bid = blockIdx.x;
    const int lid = (bid & 7) * 1536 + (bid >> 3);
    const int e = lid / 1536, rgrp = lid % 1536;
    const int sup = rgrp / 48, sub = rgrp % 48;
    const int m0 = (sup * 2 + sub / 24) * 128, n0 = (sub % 24) * 128;
    const unsigned cp = cntp[e];
    if ((unsigned)m0 >= cp) return;
    const unsigned base = offs[e];
    const float* __restrict__ W = EW1 + (size_t)e * D_HID * FFN_DIM;
    __shared__ unsigned short As[128][40];
    __shared__ unsigned short Bs[128][40];
    __shared__ unsigned stok[128];
    const int tid = threadIdx.x;
    if (tid < 128) {
        unsigned rr = (unsigned)(m0 + tid);
        stok[tid] = tokv[base + ((rr < cp) ? rr : (cp - 1u))];
    }
    __syncthreads();
    const int wv = tid >> 6, ln = tid & 63;
    const int m_off = (wv >> 1) * 64, n_off = (wv & 1) * 64;
    const int lrow = ln & 15, lkg = ln >> 4;
    const int ar = tid >> 1, ac = (tid & 1) * 16;
    const int bn = tid & 127, bq = tid >> 7;
    f32x4 acc[4][4] = {};
    const unsigned short* aptr = Xb + (size_t)stok[ar] * D_HID + ac;
    for (int k0 = 0; k0 < D_HID; k0 += 32) {
        *reinterpret_cast<uint4*>(&As[ar][ac])     = *reinterpret_cast<const uint4*>(aptr + k0);
        *reinterpret_cast<uint4*>(&As[ar][ac + 8]) = *reinterpret_cast<const uint4*>(aptr + k0 + 8);
        {
            const float* wsrc = W + (size_t)(k0 + bq * 16) * FFN_DIM + n0 + bn;
            unsigned short th[16];
            #pragma unroll
            for (int kk = 0; kk < 16; ++kk) th[kk] = f2bf(wsrc[(size_t)kk * FFN_DIM]);
            *reinterpret_cast<uint4*>(&Bs[bn][bq * 16])     = *reinterpret_cast<uint4*>(&th[0]);
            *reinterpret_cast<uint4*>(&Bs[bn][bq * 16 + 8]) = *reinterpret_cast<uint4*>(&th[8]);
        }
        __syncthreads();
        bf16x8 a[4];
        #pragma unroll
        for (int i = 0; i < 4; ++i)
            a[i] = *reinterpret_cast<const bf16x8*>(&As[m_off + i * 16 + lrow][lkg * 8]);
        #pragma unroll
        for (int j = 0; j < 4; ++j) {
            bf16x8 b = *reinterpret_cast<const bf16x8*>(&Bs[n_off + j * 16 + lrow][lkg * 8]);
            #pragma unroll
            for (int i = 0; i < 4; ++i)
                acc[i][j] = __builtin_amdgcn_mfma_f32_16x16x32_bf16(a[i], b, acc[i][j], 0, 0, 0);
        }
        __syncthreads();
    }
    const float* bias = EB1 + (size_t)e * FFN_DIM + n0;
    #pragma unroll
    for (int i = 0; i < 4; ++i)
        #pragma unroll
        for (int r = 0; r < 4; ++r) {
            unsigned rr = (unsigned)(m0 + m_off + i * 16 + lkg * 4 + r);
            if (rr < cp) {
                unsigned short* dst = H1 + (size_t)(base + rr) * FFN_DIM + n0;
                #pragma unroll
                for (int j = 0; j < 4; ++j) {
                    int c = n_off + j * 16 + lrow;
                    dst[c] = f2bf(acc[i][j][r] + bias[c]);
                }
            }
        }
}

// ======== grouped GEMM2: h1 bf16 @ bf16(ew2) -> h2 bf16 ========
// grid 3072: e = bid&7, rgrp: m-major/6n
__global__ __launch_bounds__(256) void k_gemm2(
    const unsigned short* __restrict__ H1, const float* __restrict__ EW2,
    const float* __restrict__ EB2, const unsigned* __restrict__ offs,
    const unsigned* __restrict__ cntp, unsigned short* __restrict__ H2b) {
    const int bid = blockIdx.x;
    const int lid = (bid & 7) * 384 + (bid >> 3);
    const int e = lid / 384, rgrp = lid % 384;
    const int m0 = (rgrp / 6) * 128, n0 = (rgrp % 6) * 128;
    const unsigned cp = cntp[e];
    if ((unsigned)m0 >= cp) return;
    const unsigned base = offs[e];
    const float* __restrict__ W = EW2 + (size_t)e * FFN_DIM * D_HID;
    __shared__ unsigned short As[128][40];
    __shared__ unsigned short Bs[128][40];
    const int tid = threadIdx.x;
    const int wv = tid >> 6, ln = tid & 63;
    const int m_off = (wv >> 1) * 64, n_off = (wv & 1) * 64;
    const int lrow = ln & 15, lkg = ln >> 4;
    const int ar = tid >> 1, ac = (tid & 1) * 16;
    const int bn = tid & 127, bq = tid >> 7;
    unsigned arow = (unsigned)(m0 + ar);
    if (arow >= cp) arow = cp - 1u;
    const unsigned short* aptr = H1 + (size_t)(base + arow) * FFN_DIM + ac;
    f32x4 acc[4][4] = {};
    for (int k0 = 0; k0 < FFN_DIM; k0 += 32) {
        *reinterpret_cast<uint4*>(&As[ar][ac])     = *reinterpret_cast<const uint4*>(aptr + k0);
        *reinterpret_cast<uint4*>(&As[ar][ac + 8]) = *reinterpret_cast<const uint4*>(aptr + k0 + 8);
        {
            const float* wsrc = W + (size_t)(k0 + bq * 16) * D_HID + n0 + bn;
            unsigned short th[16];
            #pragma unroll
            for (int kk = 0; kk < 16; ++kk) th[kk] = f2bf(wsrc[(size_t)kk * D_HID]);
            *reinterpret_cast<uint4*>(&Bs[bn][bq * 16])     = *reinterpret_cast<uint4*>(&th[0]);
            *reinterpret_cast<uint4*>(&Bs[bn][bq * 16 + 8]) = *reinterpret_cast<uint4*>(&th[8]);
        }
        __syncthreads();
        bf16x8 a[4];
        #pragma unroll
        for (int i = 0; i < 4; ++i)
            a[i] = *reinterpret_cast<const bf16x8*>(&As[m_off + i * 16 + lrow][lkg * 8]);
        #pragma unroll
        for (int j = 0; j < 4; ++j) {
            bf16x8 b = *reinterpret_cast<const bf16x8*>(&Bs[n_off + j * 16 + lrow][lkg * 8]);
            #pragma unroll
            for (int i = 0; i < 4; ++i)
                acc[i][j] = __builtin_amdgcn_mfma_f32_16x16x32_bf16(a[i], b, acc[i][j], 0, 0, 0);
        }
        __syncthreads();
    }
    const float* bias = EB2 + (size_t)e * D_HID + n0;
    #pragma unroll
    for (int i = 0; i < 4; ++i)
        #pragma unroll
        for (int r = 0; r < 4; ++r) {
            unsigned rr = (unsigned)(m0 + m_off + i * 16 + lkg * 4 + r);
            if (rr < cp) {
                unsigned short* dst = H2b + (size_t)(base + rr) * D_HID + n0;
                #pragma unroll
                for (int j = 0; j < 4; ++j) {
                    int c = n_off + j * 16 + lrow;
                    dst[c] = f2bf(acc[i][j][r] + bias[c]);
                }
            }
        }
}

// ======== GEMM3 MFMA: h2 bf16 @ split-bf16 W3[c][k] -> weighted atomic scatter ========
// tile 64M x 192N, BK=32; grid 1024: e = bid&7
__global__ __launch_bounds__(256) void k_gemm3(
    const unsigned short* __restrict__ H2b, const unsigned short* __restrict__ W3h,
    const unsigned short* __restrict__ W3l, const float* __restrict__ EB3,
    const unsigned* __restrict__ tokv, const unsigned* __restrict__ offs,
    const unsigned* __restrict__ cntp, const float* __restrict__ wslot,
    float* __restrict__ out) {
    const int bid = blockIdx.x;
    const int lid = (bid & 7) * 128 + (bid >> 3);
    const int e = lid >> 7, mg = lid & 127;
    const int m0 = mg * 64;
    const unsigned cp = cntp[e];
    if ((unsigned)m0 >= cp) return;
    const unsigned base = offs[e];
    __shared__ unsigned short As[64][40];
    __shared__ unsigned short Bh[192][40];
    __shared__ unsigned short Bl[192][40];
    const int tid = threadIdx.x;
    const int wv = tid >> 6, ln = tid & 63;
    const int m_off = (wv >> 1) * 32, n_off = (wv & 1) * 96;
    const int lrow = ln & 15, lkg = ln >> 4;
    const int ar = tid >> 2, ac = (tid & 3) * 8;
    unsigned arow = (unsigned)(m0 + ar);
    if (arow >= cp) arow = cp - 1u;
    const unsigned short* aptr = H2b + (size_t)(base + arow) * D_HID + ac;
    const unsigned short* w3hb = W3h + (size_t)e * 192 * D_HID;
    const unsigned short* w3lb = W3l + (size_t)e * 192 * D_HID;
    f32x4 acc[2][6] = {};
    for (int k0 = 0; k0 < D_HID; k0 += 32) {
        *reinterpret_cast<uint4*>(&As[ar][ac]) = *reinterpret_cast<const uint4*>(aptr + k0);
        #pragma unroll
        for (int q = 0; q < 3; ++q) {
            int task = tid + q * 256;
            int br = task >> 2, bs = (task & 3) * 8;
            *reinterpret_cast<uint4*>(&Bh[br][bs]) =
                *reinterpret_cast<const uint4*>(w3hb + (size_t)br * D_HID + k0 + bs);
            *reinterpret_cast<uint4*>(&Bl[br][bs]) =
                *reinterpret_cast<const uint4*>(w3lb + (size_t)br * D_HID + k0 + bs);
        }
        __syncthreads();
        bf16x8 a0 = *reinterpret_cast<const bf16x8*>(&As[m_off + lrow][lkg * 8]);
        bf16x8 a1 = *reinterpret_cast<const bf16x8*>(&As[m_off + 16 + lrow][lkg * 8]);
        #pragma unroll
        for (int j = 0; j < 6; ++j) {
            bf16x8 bh = *reinterpret_cast<const bf16x8*>(&Bh[n_off + j * 16 + lrow][lkg * 8]);
            bf16x8 bl = *reinterpret_cast<const bf16x8*>(&Bl[n_off + j * 16 + lrow][lkg * 8]);
            acc[0][j] = __builtin_amdgcn_mfma_f32_16x16x32_bf16(a0, bh, acc[0][j], 0, 0, 0);
            acc[0][j] = __builtin_amdgcn_mfma_f32_16x16x32_bf16(a0, bl, acc[0][j], 0, 0, 0);
            acc[1][j] = __builtin_amdgcn_mfma_f32_16x16x32_bf16(a1, bh, acc[1][j], 0, 0, 0);
            acc[1][j] = __builtin_amdgcn_mfma_f32_16x16x32_bf16(a1, bl, acc[1][j], 0, 0, 0);
        }
        __syncthreads();
    }
    const float* b3 = EB3 + (size_t)e * NCLS;
    #pragma unroll
    for (int i = 0; i < 2; ++i)
        #pragma unroll
        for (int r = 0; r < 4; ++r) {
            unsigned rr = (unsigned)(m0 + m_off + i * 16 + lkg * 4 + r);
            if (rr < cp) {
                unsigned slot = base + rr;
                float w = wslot[slot] * (1.0f / NSEQ);
                if (w != 0.0f) {
                    unsigned bno = tokv[slot] >> 5;
                    float* op = out + (size_t)bno * NCLS;
                    #pragma unroll
                    for (int j = 0; j < 6; ++j) {
                        int c = n_off + j * 16 + lrow;
                        if (c < NCLS) atomicAdd(op + c, w * (acc[i][j][r] + b3[c]));
                    }
                }
            }
        }
}

__global__ void k_aux(const float* __restrict__ zsum, const float* __restrict__ loadsum,
                      float* __restrict__ out) {
    if (threadIdx.x == 0) {
        float z = 0.1f * zsum[0] / (float)T_TOK;
        float lb = 0.f;
        for (int e = 0; e < NE; ++e) {
            float d = loadsum[e] / (float)T_TOK - 0.125f;
            lb += d * d;
        }
        out[OUT_N] = z + 0.1f * lb;
    }
}

extern "C" void kernel_launch(void* const* d_in, const int* in_sizes, int n_in,
                              void* d_out, int out_size, void* d_ws, size_t ws_size,
                              hipStream_t stream) {
    (void)in_sizes; (void)n_in; (void)out_size; (void)ws_size;
    const float* x    = (const float*)d_in[0];
    const float* rw1  = (const float*)d_in[1];
    const float* rb1  = (const float*)d_in[2];
    const float* rlg  = (const float*)d_in[3];
    const float* rlb  = (const float*)d_in[4];
    const float* rw2  = (const float*)d_in[5];
    const float* rb2  = (const float*)d_in[6];
    const float* ew1  = (const float*)d_in[7];
    const float* eb1  = (const float*)d_in[8];
    const float* el1g = (const float*)d_in[9];
    const float* el1b = (const float*)d_in[10];
    const float* ew2  = (const float*)d_in[11];
    const float* eb2  = (const float*)d_in[12];
    const float* el2g = (const float*)d_in[13];
    const float* el2b = (const float*)d_in[14];
    const float* ew3  = (const float*)d_in[15];
    const float* eb3  = (const float*)d_in[16];
    float* out = (float*)d_out;

    uint8_t* ws = (uint8_t*)d_ws;
    // R1 [0, 25362432): hr fp32 [8192][768] (dead after router), then h2 bf16 [16512][768]
    float* hr            = (float*)ws;
    unsigned short* h2b  = (unsigned short*)ws;
    size_t off = 25362432;
    unsigned short* rw1h = (unsigned short*)(ws + off); off += 1179648;    // [768][768]
    unsigned short* rw1l = (unsigned short*)(ws + off); off += 1179648;
    unsigned short* xb   = (unsigned short*)(ws + off); off += 12582912;   // [8192][768]
    unsigned short* w3h  = (unsigned short*)(ws + off); off += 2359296;    // [8][192][768]
    unsigned short* w3l  = (unsigned short*)(ws + off); off += 2359296;
    unsigned short* h1   = (unsigned short*)(ws + off); off += 101449728;  // [16512][3072]
    uint8_t* sb = ws + off;                                                 // ~146.5 MB
    unsigned* tokv    = (unsigned*)sb;
    unsigned* eosv    = tokv + NSLOTP;
    float*    wslot   = (float*)(eosv + NSLOTP);
    unsigned* toke    = (unsigned*)(wslot + NSLOTP);
    float*    tokw    = (float*)(toke + NSLOT);
    unsigned* counts  = (unsigned*)(tokw + NSLOT);
    unsigned* cursors = counts + NE;
    unsigned* offs    = cursors + NE;
    unsigned* cntp    = offs + NE;
    unsigned* totp    = cntp + NE;
    float*    zsum    = (float*)(totp + 1);
    float*    loadsum = zsum + 1;

    k_zero<<<dim3(192), dim3(256), 0, stream>>>(out, counts, cursors, zsum, loadsum);
    k_prep<<<dim3(3504), dim3(256), 0, stream>>>(x, rw1, ew3, xb, rw1h, rw1l, w3h, w3l);
    k_rgemm<<<dim3(384), dim3(256), 0, stream>>>(x, rw1h, rw1l, rb1, hr);
    k_ln768_f32<<<dim3(T_TOK), dim3(256), 0, stream>>>(hr, rlg, rlb);
    k_router<<<dim3(T_TOK / 4), dim3(256), 0, stream>>>(
        hr, rw2, rb2, toke, tokw, counts, zsum, loadsum);
    k_prefix<<<dim3(1), dim3(64), 0, stream>>>(counts, offs, cntp, totp, tokv, eosv, wslot);
    k_scatter<<<dim3(T_TOK / 256), dim3(256), 0, stream>>>(
        toke, tokw, offs, cursors, tokv, eosv, wslot);
    k_gemm1<<<dim3(12288), dim3(256), 0, stream>>>(xb, ew1, eb1, tokv, offs, cntp, h1);
    k_ln3072_bf16<<<dim3(NSLOTP), dim3(256), 0, stream>>>(h1, el1g, el1b, eosv, totp);
    k_gemm2<<<dim3(3072), dim3(256), 0, stream>>>(h1, ew2, eb2, offs, cntp, h2b);
    k_ln768_bf16<<<dim3(NSLOTP), dim3(256), 0, stream>>>(h2b, el2g, el2b, eosv, totp);
    k_gemm3<<<dim3(1024), dim3(256), 0, stream>>>(
        h2b, w3h, w3l, eb3, tokv, offs, cntp, wslot, out);
    k_aux<<<dim3(1), dim3(64), 0, stream>>>(zsum, loadsum, out);
}

// Round 7
// 1382.592 us; speedup vs baseline: 1.5760x; 1.0209x over previous
//
#include <hip/hip_runtime.h>
#include <hip/hip_bf16.h>
#include <stdint.h>

#define T_TOK   8192
#define D_HID   768
#define NE      8
#define FFN_DIM 3072
#define NCLS    191
#define NSEQ    32
#define NSLOT   (T_TOK * 2)
#define NSLOTP  (NSLOT + 128)
#define LN_EPS  1e-5f
#define OUT_N   (256 * NCLS)   // 48896 logits + 1 aux

typedef __bf16 bf16x8 __attribute__((ext_vector_type(8)));
typedef float  f32x4  __attribute__((ext_vector_type(4)));

static __device__ __forceinline__ float bf2f(unsigned short u) {
    return __uint_as_float(((unsigned)u) << 16);
}
static __device__ __forceinline__ unsigned short f2bf(float f) {
    return __builtin_bit_cast(unsigned short, (__bf16)f);
}
static __device__ __forceinline__ float bfround(float f) {
    return (float)((__bf16)f);
}

// ---------------- init ----------------
__global__ void k_zero(float* __restrict__ out, unsigned* __restrict__ counts,
                       unsigned* __restrict__ cursors, float* __restrict__ zsum,
                       float* __restrict__ loadsum) {
    int i = blockIdx.x * 256 + threadIdx.x;
    if (i < OUT_N + 1) out[i] = 0.0f;
    if (i < NE) { counts[i] = 0u; cursors[i] = 0u; loadsum[i] = 0.0f; }
    if (i == 0) zsum[0] = 0.0f;
}

// ---------------- fused pre-convert ----------------
// [0,3072): X->bf16 | [3072,3216): rw1->[n][k] hi/lo | [3216,3504): ew3->[c][k] hi/lo
// [3504,8112): ew1->[e][n][k] bf16 | [8112,12720): ew2->[e][n][k] bf16  (only if CVT ws)
__global__ __launch_bounds__(256) void k_prep(
    const float* __restrict__ X, const float* __restrict__ RW1, const float* __restrict__ EW3,
    const float* __restrict__ EW1, const float* __restrict__ EW2,
    unsigned short* __restrict__ Xb, unsigned short* __restrict__ RW1h,
    unsigned short* __restrict__ RW1l, unsigned short* __restrict__ W3h,
    unsigned short* __restrict__ W3l, unsigned short* __restrict__ EW1B,
    unsigned short* __restrict__ EW2B) {
    const int bid = blockIdx.x, tid = threadIdx.x;
    if (bid < 3072) {
        size_t i0 = (size_t)bid * 2048 + (size_t)tid * 8;
        float4 a = *reinterpret_cast<const float4*>(X + i0);
        float4 b = *reinterpret_cast<const float4*>(X + i0 + 4);
        unsigned short t[8] = {f2bf(a.x), f2bf(a.y), f2bf(a.z), f2bf(a.w),
                               f2bf(b.x), f2bf(b.y), f2bf(b.z), f2bf(b.w)};
        *reinterpret_cast<uint4*>(Xb + i0) = *reinterpret_cast<uint4*>(t);
        return;
    }
    __shared__ float tile[64][65];
    const int rr = tid >> 2, c4 = (tid & 3) * 16;
    if (bid < 3216) {       // rw1 [k][n] -> [n][k] hi/lo
        int t = bid - 3072, kt = t / 12, nt = t % 12;
        const float* src = RW1 + (size_t)(kt * 64 + rr) * D_HID + nt * 64 + c4;
        #pragma unroll
        for (int q = 0; q < 4; ++q) {
            float4 v = *reinterpret_cast<const float4*>(src + q * 4);
            tile[rr][c4 + q * 4 + 0] = v.x; tile[rr][c4 + q * 4 + 1] = v.y;
            tile[rr][c4 + q * 4 + 2] = v.z; tile[rr][c4 + q * 4 + 3] = v.w;
        }
        __syncthreads();
        unsigned short th[16], tl[16];
        #pragma unroll
        for (int j = 0; j < 16; ++j) {
            float f = tile[c4 + j][rr];
            th[j] = f2bf(f); tl[j] = f2bf(f - bfround(f));
        }
        size_t o = (size_t)(nt * 64 + rr) * D_HID + kt * 64 + c4;
        *reinterpret_cast<uint4*>(RW1h + o)     = *reinterpret_cast<uint4*>(&th[0]);
        *reinterpret_cast<uint4*>(RW1h + o + 8) = *reinterpret_cast<uint4*>(&th[8]);
        *reinterpret_cast<uint4*>(RW1l + o)     = *reinterpret_cast<uint4*>(&tl[0]);
        *reinterpret_cast<uint4*>(RW1l + o + 8) = *reinterpret_cast<uint4*>(&tl[8]);
    } else if (bid < 3504) {  // ew3 [e][k][c] -> [e][c(192)][k] hi/lo
        int t = bid - 3216, e = t / 36, s = t % 36, kt = s / 3, ct = s % 3;
        const float* src = EW3 + (size_t)e * D_HID * NCLS + (size_t)(kt * 64 + rr) * NCLS;
        #pragma unroll
        for (int j = 0; j < 16; ++j) {
            int c = ct * 64 + c4 + j;
            tile[rr][c4 + j] = (c < NCLS) ? src[c] : 0.0f;
        }
        __syncthreads();
        unsigned short th[16], tl[16];
        #pragma unroll
        for (int j = 0; j < 16; ++j) {
            float f = tile[c4 + j][rr];
            th[j] = f2bf(f); tl[j] = f2bf(f - bfround(f));
        }
        size_t o = (size_t)(e * 192 + ct * 64 + rr) * D_HID + kt * 64 + c4;
        *reinterpret_cast<uint4*>(W3h + o)     = *reinterpret_cast<uint4*>(&th[0]);
        *reinterpret_cast<uint4*>(W3h + o + 8) = *reinterpret_cast<uint4*>(&th[8]);
        *reinterpret_cast<uint4*>(W3l + o)     = *reinterpret_cast<uint4*>(&tl[0]);
        *reinterpret_cast<uint4*>(W3l + o + 8) = *reinterpret_cast<uint4*>(&tl[8]);
    } else if (bid < 8112) {  // ew1 [e][768][3072] -> [e][3072][768] bf16
        int t = bid - 3504, e = t / 576, s = t % 576, kt = s / 48, nt = s % 48;
        const float* src = EW1 + (size_t)e * D_HID * FFN_DIM + (size_t)(kt * 64 + rr) * FFN_DIM + nt * 64 + c4;
        #pragma unroll
        for (int q = 0; q < 4; ++q) {
            float4 v = *reinterpret_cast<const float4*>(src + q * 4);
            tile[rr][c4 + q * 4 + 0] = v.x; tile[rr][c4 + q * 4 + 1] = v.y;
            tile[rr][c4 + q * 4 + 2] = v.z; tile[rr][c4 + q * 4 + 3] = v.w;
        }
        __syncthreads();
        unsigned short th[16];
        #pragma unroll
        for (int j = 0; j < 16; ++j) th[j] = f2bf(tile[c4 + j][rr]);
        size_t o = (size_t)e * FFN_DIM * D_HID + (size_t)(nt * 64 + rr) * D_HID + kt * 64 + c4;
        *reinterpret_cast<uint4*>(EW1B + o)     = *reinterpret_cast<uint4*>(&th[0]);
        *reinterpret_cast<uint4*>(EW1B + o + 8) = *reinterpret_cast<uint4*>(&th[8]);
    } else {                  // ew2 [e][3072][768] -> [e][768][3072] bf16
        int t = bid - 8112, e = t / 576, s = t % 576, kt = s / 12, nt = s % 12;
        const float* src = EW2 + (size_t)e * FFN_DIM * D_HID + (size_t)(kt * 64 + rr) * D_HID + nt * 64 + c4;
        #pragma unroll
        for (int q = 0; q < 4; ++q) {
            float4 v = *reinterpret_cast<const float4*>(src + q * 4);
            tile[rr][c4 + q * 4 + 0] = v.x; tile[rr][c4 + q * 4 + 1] = v.y;
            tile[rr][c4 + q * 4 + 2] = v.z; tile[rr][c4 + q * 4 + 3] = v.w;
        }
        __syncthreads();
        unsigned short th[16];
        #pragma unroll
        for (int j = 0; j < 16; ++j) th[j] = f2bf(tile[c4 + j][rr]);
        size_t o = (size_t)e * D_HID * FFN_DIM + (size_t)(nt * 64 + rr) * FFN_DIM + kt * 64 + c4;
        *reinterpret_cast<uint4*>(EW2B + o)     = *reinterpret_cast<uint4*>(&th[0]);
        *reinterpret_cast<uint4*>(EW2B + o + 8) = *reinterpret_cast<uint4*>(&th[8]);
    }
}

// ======== router GEMM1: split-A x split-B MFMA (fp32-grade for exact top-2) ========
__global__ __launch_bounds__(256) void k_rgemm(
    const float* __restrict__ X, const unsigned short* __restrict__ RW1h,
    const unsigned short* __restrict__ RW1l, const float* __restrict__ bias,
    float* __restrict__ C) {
    const int bid = blockIdx.x;
    const int lid = (bid & 7) * 48 + (bid >> 3);
    const int m0 = (lid / 6) * 128, n0 = (lid % 6) * 128;
    __shared__ unsigned short Ah[128][40], Al[128][40], Bh[128][40], Bl[128][40];
    const int tid = threadIdx.x;
    const int wv = tid >> 6, ln = tid & 63;
    const int m_off = (wv >> 1) * 64, n_off = (wv & 1) * 64;
    const int lrow = ln & 15, lkg = ln >> 4;
    const int ar = tid >> 1, ac = (tid & 1) * 16;
    const float* aptr = X + (size_t)(m0 + ar) * D_HID + ac;
    const unsigned short* bph = RW1h + (size_t)(n0 + ar) * D_HID + ac;
    const unsigned short* bpl = RW1l + (size_t)(n0 + ar) * D_HID + ac;
    f32x4 acc[4][4] = {};
    for (int k0 = 0; k0 < D_HID; k0 += 32) {
        unsigned short th[16], tl[16];
        #pragma unroll
        for (int q = 0; q < 4; ++q) {
            float4 v = *reinterpret_cast<const float4*>(aptr + k0 + q * 4);
            float fv[4] = {v.x, v.y, v.z, v.w};
            #pragma unroll
            for (int j = 0; j < 4; ++j) {
                th[q * 4 + j] = f2bf(fv[j]);
                tl[q * 4 + j] = f2bf(fv[j] - bfround(fv[j]));
            }
        }
        *reinterpret_cast<uint4*>(&Ah[ar][ac])     = *reinterpret_cast<uint4*>(&th[0]);
        *reinterpret_cast<uint4*>(&Ah[ar][ac + 8]) = *reinterpret_cast<uint4*>(&th[8]);
        *reinterpret_cast<uint4*>(&Al[ar][ac])     = *reinterpret_cast<uint4*>(&tl[0]);
        *reinterpret_cast<uint4*>(&Al[ar][ac + 8]) = *reinterpret_cast<uint4*>(&tl[8]);
        *reinterpret_cast<uint4*>(&Bh[ar][ac])     = *reinterpret_cast<const uint4*>(bph + k0);
        *reinterpret_cast<uint4*>(&Bh[ar][ac + 8]) = *reinterpret_cast<const uint4*>(bph + k0 + 8);
        *reinterpret_cast<uint4*>(&Bl[ar][ac])     = *reinterpret_cast<const uint4*>(bpl + k0);
        *reinterpret_cast<uint4*>(&Bl[ar][ac + 8]) = *reinterpret_cast<const uint4*>(bpl + k0 + 8);
        __syncthreads();
        bf16x8 a_h[4], a_l[4];
        #pragma unroll
        for (int i = 0; i < 4; ++i) {
            a_h[i] = *reinterpret_cast<const bf16x8*>(&Ah[m_off + i * 16 + lrow][lkg * 8]);
            a_l[i] = *reinterpret_cast<const bf16x8*>(&Al[m_off + i * 16 + lrow][lkg * 8]);
        }
        #pragma unroll
        for (int j = 0; j < 4; ++j) {
            bf16x8 b_h = *reinterpret_cast<const bf16x8*>(&Bh[n_off + j * 16 + lrow][lkg * 8]);
            bf16x8 b_l = *reinterpret_cast<const bf16x8*>(&Bl[n_off + j * 16 + lrow][lkg * 8]);
            #pragma unroll
            for (int i = 0; i < 4; ++i) {
                acc[i][j] = __builtin_amdgcn_mfma_f32_16x16x32_bf16(a_h[i], b_h, acc[i][j], 0, 0, 0);
                acc[i][j] = __builtin_amdgcn_mfma_f32_16x16x32_bf16(a_h[i], b_l, acc[i][j], 0, 0, 0);
                acc[i][j] = __builtin_amdgcn_mfma_f32_16x16x32_bf16(a_l[i], b_h, acc[i][j], 0, 0, 0);
            }
        }
        __syncthreads();
    }
    #pragma unroll
    for (int i = 0; i < 4; ++i)
        #pragma unroll
        for (int r = 0; r < 4; ++r) {
            int row = m0 + m_off + i * 16 + lkg * 4 + r;
            float* dst = C + (size_t)row * D_HID;
            #pragma unroll
            for (int j = 0; j < 4; ++j) {
                int c = n0 + n_off + j * 16 + lrow;
                dst[c] = acc[i][j][r] + bias[c];
            }
        }
}

// ---------------- LayerNorm+ReLU, W=768 fp32 (router hidden) ----------------
__global__ __launch_bounds__(256) void k_ln768_f32(
    float* __restrict__ Xb, const float* __restrict__ g, const float* __restrict__ b) {
    const int row = blockIdx.x;
    float* x = Xb + (size_t)row * D_HID;
    const int tid = threadIdx.x;
    float v0 = x[tid], v1 = x[tid + 256], v2 = x[tid + 512];
    float s = v0 + v1 + v2, s2 = v0 * v0 + v1 * v1 + v2 * v2;
    __shared__ float rs[4], rs2[4], mv[2];
    #pragma unroll
    for (int o = 32; o > 0; o >>= 1) { s += __shfl_down(s, o); s2 += __shfl_down(s2, o); }
    const int wv = tid >> 6, ln = tid & 63;
    if (ln == 0) { rs[wv] = s; rs2[wv] = s2; }
    __syncthreads();
    if (tid == 0) {
        float ts = rs[0] + rs[1] + rs[2] + rs[3];
        float ts2 = rs2[0] + rs2[1] + rs2[2] + rs2[3];
        float m = ts / D_HID;
        mv[0] = m; mv[1] = rsqrtf(ts2 / D_HID - m * m + LN_EPS);
    }
    __syncthreads();
    float m = mv[0], r = mv[1];
    x[tid]       = fmaxf((v0 - m) * r * g[tid]       + b[tid],       0.f);
    x[tid + 256] = fmaxf((v1 - m) * r * g[tid + 256] + b[tid + 256], 0.f);
    x[tid + 512] = fmaxf((v2 - m) * r * g[tid + 512] + b[tid + 512], 0.f);
}

// ---------------- LayerNorm+ReLU, W=768 bf16 in-place (h2) ----------------
__global__ __launch_bounds__(256) void k_ln768_bf16(
    unsigned short* __restrict__ Xb, const float* __restrict__ g, const float* __restrict__ b,
    const unsigned* __restrict__ eos, const unsigned* __restrict__ totp) {
    const int row = blockIdx.x;
    if ((unsigned)row >= *totp) return;
    const unsigned e = eos[row];
    const float* gp = g + (size_t)e * D_HID;
    const float* bp = b + (size_t)e * D_HID;
    unsigned short* x = Xb + (size_t)row * D_HID;
    const int tid = threadIdx.x;
    float f[4] = {0.f, 0.f, 0.f, 0.f};
    if (tid < 192) {
        ushort4 u = *reinterpret_cast<const ushort4*>(x + tid * 4);
        f[0] = bf2f(u.x); f[1] = bf2f(u.y); f[2] = bf2f(u.z); f[3] = bf2f(u.w);
    }
    float s = f[0] + f[1] + f[2] + f[3];
    float s2 = f[0] * f[0] + f[1] * f[1] + f[2] * f[2] + f[3] * f[3];
    __shared__ float rs[4], rs2[4], mv[2];
    #pragma unroll
    for (int o = 32; o > 0; o >>= 1) { s += __shfl_down(s, o); s2 += __shfl_down(s2, o); }
    const int wv = tid >> 6, ln = tid & 63;
    if (ln == 0) { rs[wv] = s; rs2[wv] = s2; }
    __syncthreads();
    if (tid == 0) {
        float ts = rs[0] + rs[1] + rs[2] + rs[3];
        float ts2 = rs2[0] + rs2[1] + rs2[2] + rs2[3];
        float m = ts / D_HID;
        mv[0] = m; mv[1] = rsqrtf(ts2 / D_HID - m * m + LN_EPS);
    }
    __syncthreads();
    if (tid < 192) {
        float m = mv[0], r = mv[1];
        float4 gg = *reinterpret_cast<const float4*>(gp + tid * 4);
        float4 bb = *reinterpret_cast<const float4*>(bp + tid * 4);
        ushort4 o;
        o.x = f2bf(fmaxf((f[0] - m) * r * gg.x + bb.x, 0.f));
        o.y = f2bf(fmaxf((f[1] - m) * r * gg.y + bb.y, 0.f));
        o.z = f2bf(fmaxf((f[2] - m) * r * gg.z + bb.z, 0.f));
        o.w = f2bf(fmaxf((f[3] - m) * r * gg.w + bb.w, 0.f));
        *reinterpret_cast<ushort4*>(x + tid * 4) = o;
    }
}

// ---------------- LayerNorm+ReLU, W=3072 bf16 (h1) ----------------
__global__ __launch_bounds__(256) void k_ln3072_bf16(
    unsigned short* __restrict__ Xb, const float* __restrict__ g, const float* __restrict__ b,
    const unsigned* __restrict__ eos, const unsigned* __restrict__ totp) {
    const int row = blockIdx.x;
    if ((unsigned)row >= *totp) return;
    const unsigned e = eos[row];
    const float* gp = g + (size_t)e * FFN_DIM;
    const float* bp = b + (size_t)e * FFN_DIM;
    unsigned short* x = Xb + (size_t)row * FFN_DIM;
    const int tid = threadIdx.x;
    float f[12];
    #pragma unroll
    for (int i = 0; i < 3; ++i) {
        ushort4 u = *reinterpret_cast<const ushort4*>(x + (i * 256 + tid) * 4);
        f[i * 4 + 0] = bf2f(u.x); f[i * 4 + 1] = bf2f(u.y);
        f[i * 4 + 2] = bf2f(u.z); f[i * 4 + 3] = bf2f(u.w);
    }
    float s = 0.f, s2 = 0.f;
    #pragma unroll
    for (int i = 0; i < 12; ++i) { s += f[i]; s2 += f[i] * f[i]; }
    __shared__ float rs[4], rs2[4], mv[2];
    #pragma unroll
    for (int o = 32; o > 0; o >>= 1) { s += __shfl_down(s, o); s2 += __shfl_down(s2, o); }
    const int wv = tid >> 6, ln = tid & 63;
    if (ln == 0) { rs[wv] = s; rs2[wv] = s2; }
    __syncthreads();
    if (tid == 0) {
        float ts = rs[0] + rs[1] + rs[2] + rs[3];
        float ts2 = rs2[0] + rs2[1] + rs2[2] + rs2[3];
        float m = ts / FFN_DIM;
        mv[0] = m; mv[1] = rsqrtf(ts2 / FFN_DIM - m * m + LN_EPS);
    }
    __syncthreads();
    float m = mv[0], r = mv[1];
    #pragma unroll
    for (int i = 0; i < 3; ++i) {
        int off = (i * 256 + tid) * 4;
        float4 gg = *reinterpret_cast<const float4*>(gp + off);
        float4 bb = *reinterpret_cast<const float4*>(bp + off);
        ushort4 o;
        o.x = f2bf(fmaxf((f[i * 4 + 0] - m) * r * gg.x + bb.x, 0.f));
        o.y = f2bf(fmaxf((f[i * 4 + 1] - m) * r * gg.y + bb.y, 0.f));
        o.z = f2bf(fmaxf((f[i * 4 + 2] - m) * r * gg.z + bb.z, 0.f));
        o.w = f2bf(fmaxf((f[i * 4 + 3] - m) * r * gg.w + bb.w, 0.f));
        *reinterpret_cast<ushort4*>(x + off) = o;
    }
}

// ---------------- router: logits, softmax, top-2, losses, counts (fp32) ----------------
__global__ __launch_bounds__(256) void k_router(
    const float* __restrict__ HR, const float* __restrict__ RW2, const float* __restrict__ RB2,
    unsigned* __restrict__ toke, float* __restrict__ tokw,
    unsigned* __restrict__ counts, float* __restrict__ zsum, float* __restrict__ loadsum) {
    const int wv = threadIdx.x >> 6, ln = threadIdx.x & 63;
    const int t = blockIdx.x * 4 + wv;
    __shared__ float part[4][64][9];
    float p[NE] = {};
    const float* hrow = HR + (size_t)t * D_HID;
    for (int k = ln; k < D_HID; k += 64) {
        float h = hrow[k];
        const float* w = RW2 + (size_t)k * NE;
        #pragma unroll
        for (int j = 0; j < NE; ++j) p[j] += h * w[j];
    }
    #pragma unroll
    for (int j = 0; j < NE; ++j) part[wv][ln][j] = p[j];
    __syncthreads();
    if (ln < NE) {
        float sj = 0.f;
        for (int l = 0; l < 64; ++l) sj += part[wv][l][ln];
        part[wv][0][ln] = sj + RB2[ln];
    }
    __syncthreads();
    if (ln == 0) {
        float lg[NE];
        #pragma unroll
        for (int j = 0; j < NE; ++j) lg[j] = part[wv][0][j];
        float mx = lg[0];
        #pragma unroll
        for (int j = 1; j < NE; ++j) mx = fmaxf(mx, lg[j]);
        float ex[NE], se = 0.f;
        #pragma unroll
        for (int j = 0; j < NE; ++j) { ex[j] = expf(lg[j] - mx); se += ex[j]; }
        float lse = logf(se) + mx;
        atomicAdd(zsum, lse * lse);
        int i0 = 0;
        #pragma unroll
        for (int j = 1; j < NE; ++j) if (ex[j] > ex[i0]) i0 = j;
        int i1 = (i0 == 0) ? 1 : 0;
        #pragma unroll
        for (int j = 0; j < NE; ++j) if (j != i0 && ex[j] > ex[i1]) i1 = j;
        float w0 = ex[i0] / (ex[i0] + ex[i1]);
        float w1 = 1.0f - w0;
        toke[t * 2 + 0] = (unsigned)i0; toke[t * 2 + 1] = (unsigned)i1;
        tokw[t * 2 + 0] = w0;           tokw[t * 2 + 1] = w1;
        atomicAdd(&counts[i0], 1u); atomicAdd(&counts[i1], 1u);
        atomicAdd(&loadsum[i0], w0); atomicAdd(&loadsum[i1], w1);
    }
}

// ---------------- prefix with 16-padding + pad-slot fill ----------------
__global__ void k_prefix(const unsigned* __restrict__ counts, unsigned* __restrict__ offs,
                         unsigned* __restrict__ cntp, unsigned* __restrict__ totp,
                         unsigned* __restrict__ tokv, unsigned* __restrict__ eosv,
                         float* __restrict__ wslot) {
    if (threadIdx.x == 0) {
        unsigned o = 0;
        for (int e = 0; e < NE; ++e) {
            unsigned c = counts[e];
            unsigned cp = (c + 15u) & ~15u;
            offs[e] = o; cntp[e] = cp;
            for (unsigned i = c; i < cp; ++i) {
                unsigned s = o + i;
                tokv[s] = 0u; eosv[s] = (unsigned)e; wslot[s] = 0.0f;
            }
            o += cp;
        }
        totp[0] = o;
    }
}

__global__ void k_scatter(const unsigned* __restrict__ toke, const float* __restrict__ tokw,
                          const unsigned* __restrict__ offs, unsigned* __restrict__ cursors,
                          unsigned* __restrict__ tokv, unsigned* __restrict__ eosv,
                          float* __restrict__ wslot) {
    int t = blockIdx.x * 256 + threadIdx.x;
    if (t >= T_TOK) return;
    #pragma unroll
    for (int k = 0; k < 2; ++k) {
        unsigned e = toke[t * 2 + k];
        unsigned slot = offs[e] + atomicAdd(&cursors[e], 1u);
        tokv[slot] = (unsigned)t;
        eosv[slot] = e;
        wslot[slot] = tokw[t * 2 + k];
    }
}

// ======== grouped GEMM1: Xb16 gathered @ ew1 -> h1 bf16 ========
// tile 128x128, BK=32; grid 12288: e = bid&7 (XCD-pinned), m-fastest within n-strip
template<bool CVT>
__global__ __launch_bounds__(256) void k_gemm1(
    const unsigned short* __restrict__ Xb, const float* __restrict__ EW1,
    const unsigned short* __restrict__ EW1B, const float* __restrict__ EB1,
    const unsigned* __restrict__ tokv, const unsigned* __restrict__ offs,
    const unsigned* __restrict__ cntp, unsigned short* __restrict__ H1) {
    const int bid = blockIdx.x;
    const int e = bid & 7, rgrp = bid >> 3;          // [0,1536) = 24n x 64m
    const int n0 = (rgrp >> 6) * 128, m0 = (rgrp & 63) * 128;
    const unsigned cp = cntp[e];
    if ((unsigned)m0 >= cp) return;
    const unsigned base = offs[e];
    __shared__ unsigned short As[128][40];
    __shared__ unsigned short Bs[128][40];
    __shared__ unsigned stok[128];
    const int tid = threadIdx.x;
    if (tid < 128) {
        unsigned rr = (unsigned)(m0 + tid);
        stok[tid] = tokv[base + ((rr < cp) ? rr : (cp - 1u))];
    }
    __syncthreads();
    const int wv = tid >> 6, ln = tid & 63;
    const int m_off = (wv >> 1) * 64, n_off = (wv & 1) * 64;
    const int lrow = ln & 15, lkg = ln >> 4;
    const int ar = tid >> 1, ac = (tid & 1) * 16;
    const int bn = tid & 127, bq = tid >> 7;
    f32x4 acc[4][4] = {};
    const unsigned short* aptr = Xb + (size_t)stok[ar] * D_HID + ac;
    const unsigned short* bptr = EW1B + ((size_t)e * FFN_DIM + n0 + ar) * D_HID + ac;
    const float* wsrc0 = EW1 + (size_t)e * D_HID * FFN_DIM + (size_t)(bq * 16) * FFN_DIM + n0 + bn;
    for (int k0 = 0; k0 < D_HID; k0 += 32) {
        *reinterpret_cast<uint4*>(&As[ar][ac])     = *reinterpret_cast<const uint4*>(aptr + k0);
        *reinterpret_cast<uint4*>(&As[ar][ac + 8]) = *reinterpret_cast<const uint4*>(aptr + k0 + 8);
        if (CVT) {
            *reinterpret_cast<uint4*>(&Bs[ar][ac])     = *reinterpret_cast<const uint4*>(bptr + k0);
            *reinterpret_cast<uint4*>(&Bs[ar][ac + 8]) = *reinterpret_cast<const uint4*>(bptr + k0 + 8);
        } else {
            const float* wsrc = wsrc0 + (size_t)k0 * FFN_DIM;
            unsigned short th[16];
            #pragma unroll
            for (int kk = 0; kk < 16; ++kk) th[kk] = f2bf(wsrc[(size_t)kk * FFN_DIM]);
            *reinterpret_cast<uint4*>(&Bs[bn][bq * 16])     = *reinterpret_cast<uint4*>(&th[0]);
            *reinterpret_cast<uint4*>(&Bs[bn][bq * 16 + 8]) = *reinterpret_cast<uint4*>(&th[8]);
        }
        __syncthreads();
        bf16x8 a[4];
        #pragma unroll
        for (int i = 0; i < 4; ++i)
            a[i] = *reinterpret_cast<const bf16x8*>(&As[m_off + i * 16 + lrow][lkg * 8]);
        #pragma unroll
        for (int j = 0; j < 4; ++j) {
            bf16x8 b = *reinterpret_cast<const bf16x8*>(&Bs[n_off + j * 16 + lrow][lkg * 8]);
            #pragma unroll
            for (int i = 0; i < 4; ++i)
                acc[i][j] = __builtin_amdgcn_mfma_f32_16x16x32_bf16(a[i], b, acc[i][j], 0, 0, 0);
        }
        __syncthreads();
    }
    const float* bias = EB1 + (size_t)e * FFN_DIM + n0;
    #pragma unroll
    for (int i = 0; i < 4; ++i)
        #pragma unroll
        for (int r = 0; r < 4; ++r) {
            unsigned rr = (unsigned)(m0 + m_off + i * 16 + lkg * 4 + r);
            if (rr < cp) {
                unsigned short* dst = H1 + (size_t)(base + rr) * FFN_DIM + n0;
                #pragma unroll
                for (int j = 0; j < 4; ++j) {
                    int c = n_off + j * 16 + lrow;
                    dst[c] = f2bf(acc[i][j][r] + bias[c]);
                }
            }
        }
}

// ======== grouped GEMM2: h1 bf16 @ ew2 -> h2 bf16 ========
// grid 3072: e = bid&7; 8m x 6n slabs, m-fastest
template<bool CVT>
__global__ __launch_bounds__(256) void k_gemm2(
    const unsigned short* __restrict__ H1, const float* __restrict__ EW2,
    const unsigned short* __restrict__ EW2B, const float* __restrict__ EB2,
    const unsigned* __restrict__ offs, const unsigned* __restrict__ cntp,
    unsigned short* __restrict__ H2b) {
    const int bid = blockIdx.x;
    const int e = bid & 7, rgrp = bid >> 3;          // [0,384) = 8 slabs x (6n x 8m)
    const int slab = rgrp / 48, w = rgrp % 48;
    const int m0 = (slab * 8 + (w & 7)) * 128, n0 = (w >> 3) * 128;
    const unsigned cp = cntp[e];
    if ((unsigned)m0 >= cp) return;
    const unsigned base = offs[e];
    __shared__ unsigned short As[128][40];
    __shared__ unsigned short Bs[128][40];
    const int tid = threadIdx.x;
    const int wv = tid >> 6, ln = tid & 63;
    const int m_off = (wv >> 1) * 64, n_off = (wv & 1) * 64;
    const int lrow = ln & 15, lkg = ln >> 4;
    const int ar = tid >> 1, ac = (tid & 1) * 16;
    const int bn = tid & 127, bq = tid >> 7;
    unsigned arow = (unsigned)(m0 + ar);
    if (arow >= cp) arow = cp - 1u;
    const unsigned short* aptr = H1 + (size_t)(base + arow) * FFN_DIM + ac;
    const unsigned short* bptr = EW2B + ((size_t)e * D_HID + n0 + ar) * FFN_DIM + ac;
    const float* wsrc0 = EW2 + (size_t)e * FFN_DIM * D_HID + (size_t)(bq * 16) * D_HID + n0 + bn;
    f32x4 acc[4][4] = {};
    for (int k0 = 0; k0 < FFN_DIM; k0 += 32) {
        *reinterpret_cast<uint4*>(&As[ar][ac])     = *reinterpret_cast<const uint4*>(aptr + k0);
        *reinterpret_cast<uint4*>(&As[ar][ac + 8]) = *reinterpret_cast<const uint4*>(aptr + k0 + 8);
        if (CVT) {
            *reinterpret_cast<uint4*>(&Bs[ar][ac])     = *reinterpret_cast<const uint4*>(bptr + k0);
            *reinterpret_cast<uint4*>(&Bs[ar][ac + 8]) = *reinterpret_cast<const uint4*>(bptr + k0 + 8);
        } else {
            const float* wsrc = wsrc0 + (size_t)k0 * D_HID;
            unsigned short th[16];
            #pragma unroll
            for (int kk = 0; kk < 16; ++kk) th[kk] = f2bf(wsrc[(size_t)kk * D_HID]);
            *reinterpret_cast<uint4*>(&Bs[bn][bq * 16])     = *reinterpret_cast<uint4*>(&th[0]);
            *reinterpret_cast<uint4*>(&Bs[bn][bq * 16 + 8]) = *reinterpret_cast<uint4*>(&th[8]);
        }
        __syncthreads();
        bf16x8 a[4];
        #pragma unroll
        for (int i = 0; i < 4; ++i)
            a[i] = *reinterpret_cast<const bf16x8*>(&As[m_off + i * 16 + lrow][lkg * 8]);
        #pragma unroll
        for (int j = 0; j < 4; ++j) {
            bf16x8 b = *reinterpret_cast<const bf16x8*>(&Bs[n_off + j * 16 + lrow][lkg * 8]);
            #pragma unroll
            for (int i = 0; i < 4; ++i)
                acc[i][j] = __builtin_amdgcn_mfma_f32_16x16x32_bf16(a[i], b, acc[i][j], 0, 0, 0);
        }
        __syncthreads();
    }
    const float* bias = EB2 + (size_t)e * D_HID + n0;
    #pragma unroll
    for (int i = 0; i < 4; ++i)
        #pragma unroll
        for (int r = 0; r < 4; ++r) {
            unsigned rr = (unsigned)(m0 + m_off + i * 16 + lkg * 4 + r);
            if (rr < cp) {
                unsigned short* dst = H2b + (size_t)(base + rr) * D_HID + n0;
                #pragma unroll
                for (int j = 0; j < 4; ++j) {
                    int c = n_off + j * 16 + lrow;
                    dst[c] = f2bf(acc[i][j][r] + bias[c]);
                }
            }
        }
}

// ======== GEMM3 MFMA: h2 bf16 @ split-bf16 W3[c][k] -> weighted atomic scatter ========
__global__ __launch_bounds__(256) void k_gemm3(
    const unsigned short* __restrict__ H2b, const unsigned short* __restrict__ W3h,
    const unsigned short* __restrict__ W3l, const float* __restrict__ EB3,
    const unsigned* __restrict__ tokv, const unsigned* __restrict__ offs,
    const unsigned* __restrict__ cntp, const float* __restrict__ wslot,
    float* __restrict__ out) {
    const int bid = blockIdx.x;
    const int lid = (bid & 7) * 128 + (bid >> 3);
    const int e = lid >> 7, mg = lid & 127;
    const int m0 = mg * 64;
    const unsigned cp = cntp[e];
    if ((unsigned)m0 >= cp) return;
    const unsigned base = offs[e];
    __shared__ unsigned short As[64][40];
    __shared__ unsigned short Bh[192][40];
    __shared__ unsigned short Bl[192][40];
    const int tid = threadIdx.x;
    const int wv = tid >> 6, ln = tid & 63;
    const int m_off = (wv >> 1) * 32, n_off = (wv & 1) * 96;
    const int lrow = ln & 15, lkg = ln >> 4;
    const int ar = tid >> 2, ac = (tid & 3) * 8;
    unsigned arow = (unsigned)(m0 + ar);
    if (arow >= cp) arow = cp - 1u;
    const unsigned short* aptr = H2b + (size_t)(base + arow) * D_HID + ac;
    const unsigned short* w3hb = W3h + (size_t)e * 192 * D_HID;
    const unsigned short* w3lb = W3l + (size_t)e * 192 * D_HID;
    f32x4 acc[2][6] = {};
    for (int k0 = 0; k0 < D_HID; k0 += 32) {
        *reinterpret_cast<uint4*>(&As[ar][ac]) = *reinterpret_cast<const uint4*>(aptr + k0);
        #pragma unroll
        for (int q = 0; q < 3; ++q) {
            int task = tid + q * 256;
            int br = task >> 2, bs = (task & 3) * 8;
            *reinterpret_cast<uint4*>(&Bh[br][bs]) =
                *reinterpret_cast<const uint4*>(w3hb + (size_t)br * D_HID + k0 + bs);
            *reinterpret_cast<uint4*>(&Bl[br][bs]) =
                *reinterpret_cast<const uint4*>(w3lb + (size_t)br * D_HID + k0 + bs);
        }
        __syncthreads();
        bf16x8 a0 = *reinterpret_cast<const bf16x8*>(&As[m_off + lrow][lkg * 8]);
        bf16x8 a1 = *reinterpret_cast<const bf16x8*>(&As[m_off + 16 + lrow][lkg * 8]);
        #pragma unroll
        for (int j = 0; j < 6; ++j) {
            bf16x8 bh = *reinterpret_cast<const bf16x8*>(&Bh[n_off + j * 16 + lrow][lkg * 8]);
            bf16x8 bl = *reinterpret_cast<const bf16x8*>(&Bl[n_off + j * 16 + lrow][lkg * 8]);
            acc[0][j] = __builtin_amdgcn_mfma_f32_16x16x32_bf16(a0, bh, acc[0][j], 0, 0, 0);
            acc[0][j] = __builtin_amdgcn_mfma_f32_16x16x32_bf16(a0, bl, acc[0][j], 0, 0, 0);
            acc[1][j] = __builtin_amdgcn_mfma_f32_16x16x32_bf16(a1, bh, acc[1][j], 0, 0, 0);
            acc[1][j] = __builtin_amdgcn_mfma_f32_16x16x32_bf16(a1, bl, acc[1][j], 0, 0, 0);
        }
        __syncthreads();
    }
    const float* b3 = EB3 + (size_t)e * NCLS;
    #pragma unroll
    for (int i = 0; i < 2; ++i)
        #pragma unroll
        for (int r = 0; r < 4; ++r) {
            unsigned rr = (unsigned)(m0 + m_off + i * 16 + lkg * 4 + r);
            if (rr < cp) {
                unsigned slot = base + rr;
                float w = wslot[slot] * (1.0f / NSEQ);
                if (w != 0.0f) {
                    unsigned bno = tokv[slot] >> 5;
                    float* op = out + (size_t)bno * NCLS;
                    #pragma unroll
                    for (int j = 0; j < 6; ++j) {
                        int c = n_off + j * 16 + lrow;
                        if (c < NCLS) atomicAdd(op + c, w * (acc[i][j][r] + b3[c]));
                    }
                }
            }
        }
}

__global__ void k_aux(const float* __restrict__ zsum, const float* __restrict__ loadsum,
                      float* __restrict__ out) {
    if (threadIdx.x == 0) {
        float z = 0.1f * zsum[0] / (float)T_TOK;
        float lb = 0.f;
        for (int e = 0; e < NE; ++e) {
            float d = loadsum[e] / (float)T_TOK - 0.125f;
            lb += d * d;
        }
        out[OUT_N] = z + 0.1f * lb;
    }
}

extern "C" void kernel_launch(void* const* d_in, const int* in_sizes, int n_in,
                              void* d_out, int out_size, void* d_ws, size_t ws_size,
                              hipStream_t stream) {
    (void)in_sizes; (void)n_in; (void)out_size;
    const float* x    = (const float*)d_in[0];
    const float* rw1  = (const float*)d_in[1];
    const float* rb1  = (const float*)d_in[2];
    const float* rlg  = (const float*)d_in[3];
    const float* rlb  = (const float*)d_in[4];
    const float* rw2  = (const float*)d_in[5];
    const float* rb2  = (const float*)d_in[6];
    const float* ew1  = (const float*)d_in[7];
    const float* eb1  = (const float*)d_in[8];
    const float* el1g = (const float*)d_in[9];
    const float* el1b = (const float*)d_in[10];
    const float* ew2  = (const float*)d_in[11];
    const float* eb2  = (const float*)d_in[12];
    const float* el2g = (const float*)d_in[13];
    const float* el2b = (const float*)d_in[14];
    const float* ew3  = (const float*)d_in[15];
    const float* eb3  = (const float*)d_in[16];
    float* out = (float*)d_out;

    uint8_t* ws = (uint8_t*)d_ws;
    // Region A [0, 25362432): hr fp32 [8192][768] (dead after router) -> h2b bf16 [16512][768]
    float* hr            = (float*)ws;
    unsigned short* h2b  = (unsigned short*)ws;
    size_t off = 25362432;
    unsigned short* rw1h = (unsigned short*)(ws + off); off += 1179648;    // [768][768]
    unsigned short* rw1l = (unsigned short*)(ws + off); off += 1179648;
    unsigned short* xb   = (unsigned short*)(ws + off); off += 12582912;   // [8192][768]
    unsigned short* w3h  = (unsigned short*)(ws + off); off += 2359296;    // [8][192][768]
    unsigned short* w3l  = (unsigned short*)(ws + off); off += 2359296;
    // conditional bf16 weight planes (ew1b + ew2b = 75.5 MB)
    const size_t need_cvt = off + 75497472ull + 101449728ull + 400000ull;
    const bool cvt = ws_size >= need_cvt;
    unsigned short* ew1b = nullptr;
    unsigned short* ew2b = nullptr;
    if (cvt) {
        ew1b = (unsigned short*)(ws + off); off += 37748736;               // [8][3072][768]
        ew2b = (unsigned short*)(ws + off); off += 37748736;               // [8][768][3072]
    }
    unsigned short* h1   = (unsigned short*)(ws + off); off += 101449728;  // [16512][3072]
    uint8_t* sb = ws + off;
    unsigned* tokv    = (unsigned*)sb;
    unsigned* eosv    = tokv + NSLOTP;
    float*    wslot   = (float*)(eosv + NSLOTP);
    unsigned* toke    = (unsigned*)(wslot + NSLOTP);
    float*    tokw    = (float*)(toke + NSLOT);
    unsigned* counts  = (unsigned*)(tokw + NSLOT);
    unsigned* cursors = counts + NE;
    unsigned* offs    = cursors + NE;
    unsigned* cntp    = offs + NE;
    unsigned* totp    = cntp + NE;
    float*    zsum    = (float*)(totp + 1);
    float*    loadsum = zsum + 1;

    k_zero<<<dim3(192), dim3(256), 0, stream>>>(out, counts, cursors, zsum, loadsum);
    k_prep<<<dim3(cvt ? 12720 : 3504), dim3(256), 0, stream>>>(
        x, rw1, ew3, ew1, ew2, xb, rw1h, rw1l, w3h, w3l, ew1b, ew2b);
    k_rgemm<<<dim3(384), dim3(256), 0, stream>>>(x, rw1h, rw1l, rb1, hr);
    k_ln768_f32<<<dim3(T_TOK), dim3(256), 0, stream>>>(hr, rlg, rlb);
    k_router<<<dim3(T_TOK / 4), dim3(256), 0, stream>>>(
        hr, rw2, rb2, toke, tokw, counts, zsum, loadsum);
    k_prefix<<<dim3(1), dim3(64), 0, stream>>>(counts, offs, cntp, totp, tokv, eosv, wslot);
    k_scatter<<<dim3(T_TOK / 256), dim3(256), 0, stream>>>(
        toke, tokw, offs, cursors, tokv, eosv, wslot);
    if (cvt) {
        k_gemm1<true><<<dim3(12288), dim3(256), 0, stream>>>(
            xb, ew1, ew1b, eb1, tokv, offs, cntp, h1);
    } else {
        k_gemm1<false><<<dim3(12288), dim3(256), 0, stream>>>(
            xb, ew1, ew1b, eb1, tokv, offs, cntp, h1);
    }
    k_ln3072_bf16<<<dim3(NSLOTP), dim3(256), 0, stream>>>(h1, el1g, el1b, eosv, totp);
    if (cvt) {
        k_gemm2<true><<<dim3(3072), dim3(256), 0, stream>>>(
            h1, ew2, ew2b, eb2, offs, cntp, h2b);
    } else {
        k_gemm2<false><<<dim3(3072), dim3(256), 0, stream>>>(
            h1, ew2, ew2b, eb2, offs, cntp, h2b);
    }
    k_ln768_bf16<<<dim3(NSLOTP), dim3(256), 0, stream>>>(h2b, el2g, el2b, eosv, totp);
    k_gemm3<<<dim3(1024), dim3(256), 0, stream>>>(
        h2b, w3h, w3l, eb3, tokv, offs, cntp, wslot, out);
    k_aux<<<dim3(1), dim3(64), 0, stream>>>(zsum, loadsum, out);
}